// Round 2
// baseline (4160.387 us; speedup 1.0000x reference)
//
#include <hip/hip_runtime.h>
#include <hip/hip_bf16.h>
#include <math.h>

#define SEQ  512
#define BSZ  128
#define EMBD 128
#define H4   512
#define HD   128
#define NTAG 7
#define BOSX 4
#define EOSX 5
#define NEGC (-10000.0f)

template<typename T> __device__ __forceinline__ float ldf(const T* p);
template<> __device__ __forceinline__ float ldf<float>(const float* p) { return *p; }
template<> __device__ __forceinline__ float ldf<__hip_bfloat16>(const __hip_bfloat16* p) { return __bfloat162float(*p); }
template<typename T> __device__ __forceinline__ void stf(T* p, float v);
template<> __device__ __forceinline__ void stf<float>(float* p, float v) { *p = v; }
template<> __device__ __forceinline__ void stf<__hip_bfloat16>(__hip_bfloat16* p, float v) { *p = __float2bfloat16(v); }

__device__ __forceinline__ float fast_sigmoid(float x) {
    return 1.0f / (1.0f + __expf(-x));            // -x large -> exp=inf -> 0: safe
}
__device__ __forceinline__ float fast_tanh(float x) {
    const float ax = fabsf(x);
    const float e = __expf(-2.0f * ax);           // in (0,1]: safe
    return copysignf((1.0f - e) / (1.0f + e), x);
}

// ======================= K1: input projection =======================
// grid (2*BSZ, SEQ/64), block 512. Thread j owns gate row j (128 weight floats in VGPRs).
template<typename XWT>
__global__ __launch_bounds__(512, 2)
void proj_kernel(const int* __restrict__ sen, const float* __restrict__ emb,
                 const float* __restrict__ Wih_f, const float* __restrict__ b_f,
                 const float* __restrict__ Wih_b, const float* __restrict__ b_b,
                 XWT* __restrict__ xw)
{
    const int tid = threadIdx.x;
    const int chain = blockIdx.x;
    const int dir = chain & 1;
    const int b = chain >> 1;
    const int t0 = blockIdx.y * 64;
    const float* __restrict__ Wih  = dir ? Wih_b : Wih_f;
    const float* __restrict__ bias = dir ? b_b : b_f;

    __shared__ __align__(16) float xs[16][EMBD];      // 8 KB

    float4 w[32];
    {
        const float4* wr = (const float4*)(Wih + tid * EMBD);
        #pragma unroll
        for (int k = 0; k < 32; ++k) w[k] = wr[k];
    }
    const float bj = bias[tid];
    XWT* __restrict__ xw_c = xw + (size_t)chain * (SEQ * H4);

    for (int tt = 0; tt < 64; tt += 16) {
        {   // stage 16 embedding rows: each thread moves one float4
            const int row = tid >> 5;                  // 0..15
            const int col = tid & 31;                  // 0..31 float4s
            const int tok = sen[(t0 + tt + row) * BSZ + b];
            ((float4*)xs[row])[col] = ((const float4*)(emb + (size_t)tok * EMBD))[col];
        }
        __syncthreads();
        #pragma unroll 4
        for (int i = 0; i < 16; ++i) {
            const float4* xv = (const float4*)xs[i];
            float a0 = 0.f, a1 = 0.f, a2 = 0.f, a3 = 0.f;
            #pragma unroll
            for (int k = 0; k < 32; ++k) {
                const float4 x4 = xv[k];
                a0 += w[k].x * x4.x; a1 += w[k].y * x4.y;
                a2 += w[k].z * x4.z; a3 += w[k].w * x4.w;
            }
            stf(&xw_c[(t0 + tt + i) * H4 + tid], (a0 + a1) + (a2 + a3) + bj);
        }
        __syncthreads();
    }
}

// ======================= K2: LSTM recurrence =======================
// grid 2*BSZ, block 512. Sequential over t; h broadcast via LDS; Whh row in VGPRs.
template<typename XWT, typename HT>
__global__ __launch_bounds__(512, 2)
void rec_kernel(const float* __restrict__ Whh_f, const float* __restrict__ Whh_b,
                const XWT* __restrict__ xw, HT* __restrict__ hbuf)
{
    const int tid = threadIdx.x;
    const int chain = blockIdx.x;
    const int dir = chain & 1;
    const int b = chain >> 1;
    const float* __restrict__ Whh = dir ? Whh_b : Whh_f;

    __shared__ __align__(16) float h_lds[HD];
    __shared__ __align__(16) float gate_lds[H4];

    float4 w[32];
    {
        const float4* wr = (const float4*)(Whh + tid * HD);
        #pragma unroll
        for (int k = 0; k < 32; ++k) w[k] = wr[k];
    }
    if (tid < HD) h_lds[tid] = 0.0f;
    float c = 0.0f;
    const XWT* __restrict__ xw_c = xw + (size_t)chain * (SEQ * H4);
    HT* __restrict__ hb_c = hbuf + (size_t)(dir * BSZ + b) * (SEQ * HD);
    const int gtype = tid >> 7;                        // 0:i 1:f 2:g 3:o
    __syncthreads();

    int t = dir ? (SEQ - 1) : 0;
    const int ts = dir ? -1 : 1;
    float xv0 = ldf(&xw_c[t * H4 + tid]);              // depth-2 prefetch pipeline
    float xv1 = ldf(&xw_c[(t + ts) * H4 + tid]);
    for (int s = 0; s < SEQ; ++s) {
        float pf = 0.0f;
        if (s + 2 < SEQ) pf = ldf(&xw_c[(t + 2 * ts) * H4 + tid]);
        const float4* hv = (const float4*)h_lds;       // uniform-address broadcast
        float a0 = 0.f, a1 = 0.f, a2 = 0.f, a3 = 0.f;
        #pragma unroll
        for (int k = 0; k < 32; ++k) {
            const float4 h4 = hv[k];
            a0 += w[k].x * h4.x; a1 += w[k].y * h4.y;
            a2 += w[k].z * h4.z; a3 += w[k].w * h4.w;
        }
        const float g = (a0 + a1) + (a2 + a3) + xv0;
        gate_lds[tid] = (gtype == 2) ? fast_tanh(g) : fast_sigmoid(g);
        __syncthreads();
        if (tid < HD) {
            const float gi = gate_lds[tid];
            const float gf = gate_lds[HD + tid];
            const float gg = gate_lds[2 * HD + tid];
            const float go = gate_lds[3 * HD + tid];
            c = gf * c + gi * gg;
            const float h = go * fast_tanh(c);
            h_lds[tid] = h;
            stf(&hb_c[t * HD + tid], h);
        }
        t += ts;
        xv0 = xv1; xv1 = pf;
        __syncthreads();
    }
}

// ======================= K3: emissions =======================
// grid SEQ, block 1024 = 128 b x 8 k. ft layout: [b][t][8] for streaming in K4.
template<typename HT>
__global__ __launch_bounds__(1024, 2)
void emis_kernel(const HT* __restrict__ hbuf, const float* __restrict__ W_out,
                 const float* __restrict__ b_out, float* __restrict__ ft)
{
    const int t = blockIdx.x;
    const int b = threadIdx.x >> 3;
    const int k = threadIdx.x & 7;
    const HT* __restrict__ hf = hbuf + (size_t)b * (SEQ * HD) + t * HD;
    const HT* __restrict__ hb = hbuf + (size_t)(BSZ + b) * (SEQ * HD) + t * HD;
    float v = 0.0f;
    if (k < NTAG) {
        const float* __restrict__ wk = W_out + k * 256;
        float a0 = 0.f, a1 = 0.f;
        #pragma unroll
        for (int u = 0; u < HD; u += 2) {
            a0 += ldf(&hf[u]) * wk[u]      + ldf(&hb[u])     * wk[HD + u];
            a1 += ldf(&hf[u + 1]) * wk[u + 1] + ldf(&hb[u + 1]) * wk[HD + u + 1];
        }
        v = a0 + a1 + b_out[k];
    }
    ft[(size_t)b * (SEQ * 8) + t * 8 + k] = v;
}

// ======================= K4: Viterbi scan + backtrace =======================
// grid BSZ, block 64 (one wave): lane = next*8 + prev.
__global__ __launch_bounds__(64, 1)
void vit_kernel(const float* __restrict__ ft, const float* __restrict__ trans,
                float* __restrict__ out)
{
    const int b = blockIdx.x;
    const int lane = threadIdx.x;
    __shared__ __align__(16) float ftl[SEQ * 8];
    __shared__ int bptr_lds[SEQ * 8];

    {   // stage this chain's emissions: 16 KB coalesced
        const float4* src = (const float4*)(ft + (size_t)b * (SEQ * 8));
        float4* dst = (float4*)ftl;
        #pragma unroll
        for (int i = 0; i < SEQ * 2 / 64; ++i) dst[lane + i * 64] = src[lane + i * 64];
    }
    __syncthreads();

    const int next = lane >> 3;
    const int prev = lane & 7;
    const bool pv = (prev < NTAG);
    const bool nv = (next < NTAG);
    const float trv = (pv && nv) ? trans[next * NTAG + prev] : -3.0e38f;
    float fvp = pv ? ((prev == BOSX) ? 0.0f : NEGC) : -3.0e38f;
    for (int t = 0; t < SEQ; ++t) {
        float m = fvp + trv;
        int am = prev;
        #pragma unroll
        for (int off = 1; off < 8; off <<= 1) {          // first-max-index semantics
            const float om = __shfl_xor(m, off);
            const int oa = __shfl_xor(am, off);
            if (om > m || (om == m && oa < am)) { m = om; am = oa; }
        }
        const float fvnew = m + ftl[t * 8 + next];
        if (prev == 0) bptr_lds[t * 8 + next] = am;
        fvp = __shfl(fvnew, prev << 3);
        if (!pv) fvp = -3.0e38f;
    }
    float term = pv ? (fvp + trans[EOSX * NTAG + prev]) : -3.0e38f;
    int am = prev;
    #pragma unroll
    for (int off = 1; off < 8; off <<= 1) {
        const float om = __shfl_xor(term, off);
        const int oa = __shfl_xor(am, off);
        if (om > term || (om == term && oa < am)) { term = om; am = oa; }
    }
    if (lane == 0) {
        out[b] = term;
        int cur = am;
        for (int t = SEQ - 1; t >= 0; --t) {
            out[BSZ + t * BSZ + b] = (float)cur;
            cur = bptr_lds[t * 8 + cur];
        }
    }
}

// ======================= launch =======================
template<typename XWT, typename HT>
static void run_all(const int* sen, const float* emb,
                    const float* Wih_f, const float* Whh_f, const float* b_f,
                    const float* Wih_b, const float* Whh_b, const float* b_b,
                    const float* W_out, const float* b_out, const float* trans,
                    XWT* xw, HT* hb, float* ft, float* out, hipStream_t stream)
{
    proj_kernel<XWT><<<dim3(2 * BSZ, SEQ / 64), dim3(512), 0, stream>>>(
        sen, emb, Wih_f, b_f, Wih_b, b_b, xw);
    rec_kernel<XWT, HT><<<dim3(2 * BSZ), dim3(512), 0, stream>>>(
        Whh_f, Whh_b, xw, hb);
    emis_kernel<HT><<<dim3(SEQ), dim3(1024), 0, stream>>>(hb, W_out, b_out, ft);
    vit_kernel<<<dim3(BSZ), dim3(64), 0, stream>>>(ft, trans, out);
}

extern "C" void kernel_launch(void* const* d_in, const int* in_sizes, int n_in,
                              void* d_out, int out_size, void* d_ws, size_t ws_size,
                              hipStream_t stream)
{
    const int*   sen   = (const int*)d_in[0];
    const float* emb   = (const float*)d_in[1];
    const float* Wih_f = (const float*)d_in[2];
    const float* Whh_f = (const float*)d_in[3];
    const float* b_f   = (const float*)d_in[4];
    const float* Wih_b = (const float*)d_in[5];
    const float* Whh_b = (const float*)d_in[6];
    const float* b_b   = (const float*)d_in[7];
    const float* W_out = (const float*)d_in[8];
    const float* b_out = (const float*)d_in[9];
    const float* trans = (const float*)d_in[10];
    float* out = (float*)d_out;

    char* ws = (char*)d_ws;
    const size_t xw_elems = (size_t)2 * BSZ * SEQ * H4;   // 67,108,864
    const size_t h_elems  = (size_t)2 * BSZ * SEQ * HD;   // 16,777,216
    const size_t ft_bytes = (size_t)BSZ * SEQ * 8 * 4;    // 2 MB

    if (ws_size >= xw_elems * 4 + h_elems * 4 + ft_bytes) {
        float* xw = (float*)ws;
        float* hb = (float*)(ws + xw_elems * 4);
        float* ft = (float*)(ws + xw_elems * 4 + h_elems * 4);
        run_all<float, float>(sen, emb, Wih_f, Whh_f, b_f, Wih_b, Whh_b, b_b,
                              W_out, b_out, trans, xw, hb, ft, out, stream);
    } else if (ws_size >= xw_elems * 2 + h_elems * 4 + ft_bytes) {
        __hip_bfloat16* xw = (__hip_bfloat16*)ws;
        float* hb = (float*)(ws + xw_elems * 2);
        float* ft = (float*)(ws + xw_elems * 2 + h_elems * 4);
        run_all<__hip_bfloat16, float>(sen, emb, Wih_f, Whh_f, b_f, Wih_b, Whh_b, b_b,
                                       W_out, b_out, trans, xw, hb, ft, out, stream);
    } else {
        __hip_bfloat16* xw = (__hip_bfloat16*)ws;
        __hip_bfloat16* hb = (__hip_bfloat16*)(ws + xw_elems * 2);
        float* ft = (float*)(ws + xw_elems * 2 + h_elems * 2);
        run_all<__hip_bfloat16, __hip_bfloat16>(sen, emb, Wih_f, Whh_f, b_f, Wih_b, Whh_b, b_b,
                                                W_out, b_out, trans, xw, hb, ft, out, stream);
    }
}

// Round 3
// 3503.830 us; speedup vs baseline: 1.1874x; 1.1874x over previous
//
#include <hip/hip_runtime.h>
#include <hip/hip_bf16.h>
#include <math.h>

#define SEQ  512
#define BSZ  128
#define EMBD 128
#define H4   512
#define HD   128
#define NTAG 7
#define BOSX 4
#define EOSX 5
#define NEGC (-10000.0f)

template<typename T> __device__ __forceinline__ float ldf(const T* p);
template<> __device__ __forceinline__ float ldf<float>(const float* p) { return *p; }
template<> __device__ __forceinline__ float ldf<__hip_bfloat16>(const __hip_bfloat16* p) { return __bfloat162float(*p); }
template<typename T> __device__ __forceinline__ void stf(T* p, float v);
template<> __device__ __forceinline__ void stf<float>(float* p, float v) { *p = v; }
template<> __device__ __forceinline__ void stf<__hip_bfloat16>(__hip_bfloat16* p, float v) { *p = __float2bfloat16(v); }

__device__ __forceinline__ float fast_sigmoid(float x) {
    return 1.0f / (1.0f + __expf(-x));            // -x large -> exp=inf -> 0: safe
}
__device__ __forceinline__ float fast_tanh(float x) {
    const float ax = fabsf(x);
    const float e = __expf(-2.0f * ax);           // in (0,1]: safe
    return copysignf((1.0f - e) / (1.0f + e), x);
}

// ======================= K1: input projection =======================
// grid (2*BSZ, SEQ/64), block 512. Thread j owns gate row j: 128 weight floats
// MUST stay register-resident -> launch_bounds(512,1) gives the 256-VGPR budget.
// (512,2) caps at 128 VGPRs and spills w[] to scratch: R2 showed 6.5 GB FETCH.
template<typename XWT>
__global__ __launch_bounds__(512, 1)
void proj_kernel(const int* __restrict__ sen, const float* __restrict__ emb,
                 const float* __restrict__ Wih_f, const float* __restrict__ b_f,
                 const float* __restrict__ Wih_b, const float* __restrict__ b_b,
                 XWT* __restrict__ xw)
{
    const int tid = threadIdx.x;
    const int chain = blockIdx.x;
    const int dir = chain & 1;
    const int b = chain >> 1;
    const int t0 = blockIdx.y * 64;
    const float* __restrict__ Wih  = dir ? Wih_b : Wih_f;
    const float* __restrict__ bias = dir ? b_b : b_f;

    __shared__ __align__(16) float xs[16][EMBD];      // 8 KB

    float4 w[32];                                     // 128 VGPRs, register-resident
    {
        const float4* wr = (const float4*)(Wih + tid * EMBD);
        #pragma unroll
        for (int k = 0; k < 32; ++k) w[k] = wr[k];
    }
    const float bj = bias[tid];
    XWT* __restrict__ xw_c = xw + (size_t)chain * (SEQ * H4);

    for (int tt = 0; tt < 64; tt += 16) {
        {   // stage 16 embedding rows: each thread moves one float4
            const int row = tid >> 5;                  // 0..15
            const int col = tid & 31;                  // 0..31 float4s
            const int tok = sen[(t0 + tt + row) * BSZ + b];
            ((float4*)xs[row])[col] = ((const float4*)(emb + (size_t)tok * EMBD))[col];
        }
        __syncthreads();
        for (int i = 0; i < 16; ++i) {
            const float4* xv = (const float4*)xs[i];
            float a0 = 0.f, a1 = 0.f, a2 = 0.f, a3 = 0.f;
            #pragma unroll
            for (int k = 0; k < 32; ++k) {
                const float4 x4 = xv[k];
                a0 += w[k].x * x4.x; a1 += w[k].y * x4.y;
                a2 += w[k].z * x4.z; a3 += w[k].w * x4.w;
            }
            stf(&xw_c[(t0 + tt + i) * H4 + tid], (a0 + a1) + (a2 + a3) + bj);
        }
        __syncthreads();
    }
}

// ======================= K2: LSTM recurrence =======================
// grid 2*BSZ (=256 -> 1 block/CU), block 512. Sequential over t; h broadcast
// via LDS; Whh row register-resident (launch_bounds(512,1), see K1 note).
template<typename XWT, typename HT>
__global__ __launch_bounds__(512, 1)
void rec_kernel(const float* __restrict__ Whh_f, const float* __restrict__ Whh_b,
                const XWT* __restrict__ xw, HT* __restrict__ hbuf)
{
    const int tid = threadIdx.x;
    const int chain = blockIdx.x;
    const int dir = chain & 1;
    const int b = chain >> 1;
    const float* __restrict__ Whh = dir ? Whh_b : Whh_f;

    __shared__ __align__(16) float h_lds[HD];
    __shared__ __align__(16) float gate_lds[H4];

    float4 w[32];                                     // 128 VGPRs, register-resident
    {
        const float4* wr = (const float4*)(Whh + tid * HD);
        #pragma unroll
        for (int k = 0; k < 32; ++k) w[k] = wr[k];
    }
    if (tid < HD) h_lds[tid] = 0.0f;
    float c = 0.0f;
    const XWT* __restrict__ xw_c = xw + (size_t)chain * (SEQ * H4);
    HT* __restrict__ hb_c = hbuf + (size_t)(dir * BSZ + b) * (SEQ * HD);
    const int gtype = tid >> 7;                        // 0:i 1:f 2:g 3:o (wave-uniform)
    __syncthreads();

    int t = dir ? (SEQ - 1) : 0;
    const int ts = dir ? -1 : 1;
    float xv0 = ldf(&xw_c[t * H4 + tid]);              // depth-2 prefetch pipeline
    float xv1 = ldf(&xw_c[(t + ts) * H4 + tid]);
    for (int s = 0; s < SEQ; ++s) {
        float pf = 0.0f;
        if (s + 2 < SEQ) pf = ldf(&xw_c[(t + 2 * ts) * H4 + tid]);
        const float4* hv = (const float4*)h_lds;       // uniform-address broadcast
        float a0 = 0.f, a1 = 0.f, a2 = 0.f, a3 = 0.f;
        #pragma unroll
        for (int k = 0; k < 32; ++k) {
            const float4 h4 = hv[k];
            a0 += w[k].x * h4.x; a1 += w[k].y * h4.y;
            a2 += w[k].z * h4.z; a3 += w[k].w * h4.w;
        }
        const float g = (a0 + a1) + (a2 + a3) + xv0;
        gate_lds[tid] = (gtype == 2) ? fast_tanh(g) : fast_sigmoid(g);
        __syncthreads();
        if (tid < HD) {
            const float gi = gate_lds[tid];
            const float gf = gate_lds[HD + tid];
            const float gg = gate_lds[2 * HD + tid];
            const float go = gate_lds[3 * HD + tid];
            c = gf * c + gi * gg;
            const float h = go * fast_tanh(c);
            h_lds[tid] = h;
            stf(&hb_c[t * HD + tid], h);
        }
        t += ts;
        xv0 = xv1; xv1 = pf;
        __syncthreads();
    }
}

// ======================= K3: emissions =======================
// grid SEQ, block 1024 = 128 b x 8 k. ft layout: [b][t][8] for streaming in K4.
template<typename HT>
__global__ __launch_bounds__(1024, 1)
void emis_kernel(const HT* __restrict__ hbuf, const float* __restrict__ W_out,
                 const float* __restrict__ b_out, float* __restrict__ ft)
{
    const int t = blockIdx.x;
    const int b = threadIdx.x >> 3;
    const int k = threadIdx.x & 7;
    const HT* __restrict__ hf = hbuf + (size_t)b * (SEQ * HD) + t * HD;
    const HT* __restrict__ hb = hbuf + (size_t)(BSZ + b) * (SEQ * HD) + t * HD;
    float v = 0.0f;
    if (k < NTAG) {
        const float* __restrict__ wk = W_out + k * 256;
        float a0 = 0.f, a1 = 0.f;
        #pragma unroll
        for (int u = 0; u < HD; u += 2) {
            a0 += ldf(&hf[u]) * wk[u]      + ldf(&hb[u])     * wk[HD + u];
            a1 += ldf(&hf[u + 1]) * wk[u + 1] + ldf(&hb[u + 1]) * wk[HD + u + 1];
        }
        v = a0 + a1 + b_out[k];
    }
    ft[(size_t)b * (SEQ * 8) + t * 8 + k] = v;
}

// ======================= K4: Viterbi scan + backtrace =======================
// grid BSZ, block 64 (one wave): lane = next*8 + prev.
__global__ __launch_bounds__(64, 1)
void vit_kernel(const float* __restrict__ ft, const float* __restrict__ trans,
                float* __restrict__ out)
{
    const int b = blockIdx.x;
    const int lane = threadIdx.x;
    __shared__ __align__(16) float ftl[SEQ * 8];
    __shared__ int bptr_lds[SEQ * 8];

    {   // stage this chain's emissions: 16 KB coalesced
        const float4* src = (const float4*)(ft + (size_t)b * (SEQ * 8));
        float4* dst = (float4*)ftl;
        #pragma unroll
        for (int i = 0; i < SEQ * 2 / 64; ++i) dst[lane + i * 64] = src[lane + i * 64];
    }
    __syncthreads();

    const int next = lane >> 3;
    const int prev = lane & 7;
    const bool pv = (prev < NTAG);
    const bool nv = (next < NTAG);
    const float trv = (pv && nv) ? trans[next * NTAG + prev] : -3.0e38f;
    float fvp = pv ? ((prev == BOSX) ? 0.0f : NEGC) : -3.0e38f;
    for (int t = 0; t < SEQ; ++t) {
        float m = fvp + trv;
        int am = prev;
        #pragma unroll
        for (int off = 1; off < 8; off <<= 1) {          // first-max-index semantics
            const float om = __shfl_xor(m, off);
            const int oa = __shfl_xor(am, off);
            if (om > m || (om == m && oa < am)) { m = om; am = oa; }
        }
        const float fvnew = m + ftl[t * 8 + next];
        if (prev == 0) bptr_lds[t * 8 + next] = am;
        fvp = __shfl(fvnew, prev << 3);
        if (!pv) fvp = -3.0e38f;
    }
    float term = pv ? (fvp + trans[EOSX * NTAG + prev]) : -3.0e38f;
    int am = prev;
    #pragma unroll
    for (int off = 1; off < 8; off <<= 1) {
        const float om = __shfl_xor(term, off);
        const int oa = __shfl_xor(am, off);
        if (om > term || (om == term && oa < am)) { term = om; am = oa; }
    }
    if (lane == 0) {
        out[b] = term;
        int cur = am;
        for (int t = SEQ - 1; t >= 0; --t) {
            out[BSZ + t * BSZ + b] = (float)cur;
            cur = bptr_lds[t * 8 + cur];
        }
    }
}

// ======================= launch =======================
template<typename XWT, typename HT>
static void run_all(const int* sen, const float* emb,
                    const float* Wih_f, const float* Whh_f, const float* b_f,
                    const float* Wih_b, const float* Whh_b, const float* b_b,
                    const float* W_out, const float* b_out, const float* trans,
                    XWT* xw, HT* hb, float* ft, float* out, hipStream_t stream)
{
    proj_kernel<XWT><<<dim3(2 * BSZ, SEQ / 64), dim3(512), 0, stream>>>(
        sen, emb, Wih_f, b_f, Wih_b, b_b, xw);
    rec_kernel<XWT, HT><<<dim3(2 * BSZ), dim3(512), 0, stream>>>(
        Whh_f, Whh_b, xw, hb);
    emis_kernel<HT><<<dim3(SEQ), dim3(1024), 0, stream>>>(hb, W_out, b_out, ft);
    vit_kernel<<<dim3(BSZ), dim3(64), 0, stream>>>(ft, trans, out);
}

extern "C" void kernel_launch(void* const* d_in, const int* in_sizes, int n_in,
                              void* d_out, int out_size, void* d_ws, size_t ws_size,
                              hipStream_t stream)
{
    const int*   sen   = (const int*)d_in[0];
    const float* emb   = (const float*)d_in[1];
    const float* Wih_f = (const float*)d_in[2];
    const float* Whh_f = (const float*)d_in[3];
    const float* b_f   = (const float*)d_in[4];
    const float* Wih_b = (const float*)d_in[5];
    const float* Whh_b = (const float*)d_in[6];
    const float* b_b   = (const float*)d_in[7];
    const float* W_out = (const float*)d_in[8];
    const float* b_out = (const float*)d_in[9];
    const float* trans = (const float*)d_in[10];
    float* out = (float*)d_out;

    char* ws = (char*)d_ws;
    const size_t xw_elems = (size_t)2 * BSZ * SEQ * H4;   // 67,108,864
    const size_t h_elems  = (size_t)2 * BSZ * SEQ * HD;   // 16,777,216
    const size_t ft_bytes = (size_t)BSZ * SEQ * 8 * 4;    // 2 MB

    if (ws_size >= xw_elems * 4 + h_elems * 4 + ft_bytes) {
        float* xw = (float*)ws;
        float* hb = (float*)(ws + xw_elems * 4);
        float* ft = (float*)(ws + xw_elems * 4 + h_elems * 4);
        run_all<float, float>(sen, emb, Wih_f, Whh_f, b_f, Wih_b, Whh_b, b_b,
                              W_out, b_out, trans, xw, hb, ft, out, stream);
    } else if (ws_size >= xw_elems * 2 + h_elems * 4 + ft_bytes) {
        __hip_bfloat16* xw = (__hip_bfloat16*)ws;
        float* hb = (float*)(ws + xw_elems * 2);
        float* ft = (float*)(ws + xw_elems * 2 + h_elems * 4);
        run_all<__hip_bfloat16, float>(sen, emb, Wih_f, Whh_f, b_f, Wih_b, Whh_b, b_b,
                                       W_out, b_out, trans, xw, hb, ft, out, stream);
    } else {
        __hip_bfloat16* xw = (__hip_bfloat16*)ws;
        __hip_bfloat16* hb = (__hip_bfloat16*)(ws + xw_elems * 2);
        float* ft = (float*)(ws + xw_elems * 2 + h_elems * 2);
        run_all<__hip_bfloat16, __hip_bfloat16>(sen, emb, Wih_f, Whh_f, b_f, Wih_b, Whh_b, b_b,
                                                W_out, b_out, trans, xw, hb, ft, out, stream);
    }
}

// Round 4
// 1652.484 us; speedup vs baseline: 2.5177x; 2.1203x over previous
//
#include <hip/hip_runtime.h>
#include <hip/hip_bf16.h>
#include <math.h>

#define SEQ  512
#define BSZ  128
#define EMBD 128
#define H4   512
#define HD   128
#define NTAG 7
#define BOSX 4
#define EOSX 5
#define NEGC (-10000.0f)

template<typename T> __device__ __forceinline__ float ldf(const T* p);
template<> __device__ __forceinline__ float ldf<float>(const float* p) { return *p; }
template<> __device__ __forceinline__ float ldf<__hip_bfloat16>(const __hip_bfloat16* p) { return __bfloat162float(*p); }
template<typename T> __device__ __forceinline__ void stf(T* p, float v);
template<> __device__ __forceinline__ void stf<float>(float* p, float v) { *p = v; }
template<> __device__ __forceinline__ void stf<__hip_bfloat16>(__hip_bfloat16* p, float v) { *p = __float2bfloat16(v); }

__device__ __forceinline__ float fast_sigmoid(float x) {
    return 1.0f / (1.0f + __expf(-x));            // -x large -> exp=inf -> 0: safe
}
__device__ __forceinline__ float fast_tanh(float x) {
    const float ax = fabsf(x);
    const float e = __expf(-2.0f * ax);           // in (0,1]: safe
    return copysignf((1.0f - e) / (1.0f + e), x);
}

// ======================= K1: input projection =======================
// grid (2*BSZ, SEQ/64), block 1024 = 512 rows x 2 halves. Each thread holds a
// 64-float HALF weight row (64 VGPRs) -- the compiler caps us at 128 VGPRs
// (R2/R3: 128-reg arrays spill -> 3.6 GB scratch FETCH), so stay under it.
// Halves combined with one __shfl_xor (lanes 2r,2r+1 same wave).
template<typename XWT>
__global__ __launch_bounds__(1024, 1)
void proj_kernel(const int* __restrict__ sen, const float* __restrict__ emb,
                 const float* __restrict__ Wih_f, const float* __restrict__ b_f,
                 const float* __restrict__ Wih_b, const float* __restrict__ b_b,
                 XWT* __restrict__ xw)
{
    const int tid  = threadIdx.x;
    const int row  = tid >> 1;       // 0..511 gate row
    const int half = tid & 1;        // 0..1   K-half
    const int chain = blockIdx.x;
    const int dir = chain & 1;
    const int b = chain >> 1;
    const int t0 = blockIdx.y * 64;
    const float* __restrict__ Wih  = dir ? Wih_b : Wih_f;
    const float* __restrict__ bias = dir ? b_b : b_f;

    __shared__ __align__(16) float xs[32][EMBD];      // 16 KB

    float4 w[16];                                     // 64 VGPRs: half weight row
    {
        const float4* wr = (const float4*)(Wih + row * EMBD + half * 64);
        #pragma unroll
        for (int k = 0; k < 16; ++k) w[k] = wr[k];
    }
    const float bj = bias[row];
    XWT* __restrict__ xw_c = xw + (size_t)chain * (SEQ * H4);

    for (int tt = 0; tt < 64; tt += 32) {
        {   // stage 32 embedding rows: each thread moves one float4
            const int srow = tid >> 5;                 // 0..31
            const int col = tid & 31;                  // 0..31 float4s
            const int tok = sen[(t0 + tt + srow) * BSZ + b];
            ((float4*)xs[srow])[col] = ((const float4*)(emb + (size_t)tok * EMBD))[col];
        }
        __syncthreads();
        for (int i = 0; i < 32; ++i) {
            const float4* xv = (const float4*)(xs[i] + (half << 6));
            float a0 = 0.f, a1 = 0.f, a2 = 0.f, a3 = 0.f;
            #pragma unroll
            for (int k = 0; k < 16; ++k) {
                const float4 x4 = xv[k];
                a0 += w[k].x * x4.x; a1 += w[k].y * x4.y;
                a2 += w[k].z * x4.z; a3 += w[k].w * x4.w;
            }
            float tot = (a0 + a1) + (a2 + a3);
            tot += __shfl_xor(tot, 1);                 // combine the two halves
            if (half == 0)
                stf(&xw_c[(t0 + tt + i) * H4 + row], tot + bj);
        }
        __syncthreads();
    }
}

// ======================= K2: LSTM recurrence =======================
// grid 2*BSZ (1 block/CU), block 1024 = 512 rows x 2 halves (same split as K1
// to stay under the 128-VGPR cap). h broadcast via LDS (2-addr broadcast reads
// are bank-conflict-free); c/h state lives in threads 0..127.
template<typename XWT, typename HT>
__global__ __launch_bounds__(1024, 1)
void rec_kernel(const float* __restrict__ Whh_f, const float* __restrict__ Whh_b,
                const XWT* __restrict__ xw, HT* __restrict__ hbuf)
{
    const int tid  = threadIdx.x;
    const int row  = tid >> 1;
    const int half = tid & 1;
    const int chain = blockIdx.x;
    const int dir = chain & 1;
    const int b = chain >> 1;
    const float* __restrict__ Whh = dir ? Whh_b : Whh_f;

    __shared__ __align__(16) float h_lds[HD];
    __shared__ __align__(16) float gate_lds[H4];

    float4 w[16];                                     // 64 VGPRs: half weight row
    {
        const float4* wr = (const float4*)(Whh + row * HD + half * 64);
        #pragma unroll
        for (int k = 0; k < 16; ++k) w[k] = wr[k];
    }
    if (tid < HD) h_lds[tid] = 0.0f;
    float c = 0.0f;
    const XWT* __restrict__ xw_c = xw + (size_t)chain * (SEQ * H4);
    HT* __restrict__ hb_c = hbuf + (size_t)(dir * BSZ + b) * (SEQ * HD);
    const int gtype = row >> 7;                        // 0:i 1:f 2:g 3:o (wave-uniform)
    __syncthreads();

    int t = dir ? (SEQ - 1) : 0;
    const int ts = dir ? -1 : 1;
    // depth-2 xw prefetch, even lanes only (they add xw to the gate)
    float xv0 = 0.f, xv1 = 0.f;
    if (half == 0) {
        xv0 = ldf(&xw_c[t * H4 + row]);
        xv1 = ldf(&xw_c[(t + ts) * H4 + row]);
    }
    for (int s = 0; s < SEQ; ++s) {
        float pf = 0.0f;
        if (half == 0 && s + 2 < SEQ) pf = ldf(&xw_c[(t + 2 * ts) * H4 + row]);
        const float4* hv = (const float4*)(h_lds + (half << 6));
        float a0 = 0.f, a1 = 0.f, a2 = 0.f, a3 = 0.f;
        #pragma unroll
        for (int k = 0; k < 16; ++k) {
            const float4 h4 = hv[k];
            a0 += w[k].x * h4.x; a1 += w[k].y * h4.y;
            a2 += w[k].z * h4.z; a3 += w[k].w * h4.w;
        }
        float g = (a0 + a1) + (a2 + a3);
        g += __shfl_xor(g, 1);                         // combine halves
        if (half == 0) {
            g += xv0;
            gate_lds[row] = (gtype == 2) ? fast_tanh(g) : fast_sigmoid(g);
        }
        __syncthreads();
        if (tid < HD) {
            const float gi = gate_lds[tid];
            const float gf = gate_lds[HD + tid];
            const float gg = gate_lds[2 * HD + tid];
            const float go = gate_lds[3 * HD + tid];
            c = gf * c + gi * gg;
            const float h = go * fast_tanh(c);
            h_lds[tid] = h;
            stf(&hb_c[t * HD + tid], h);
        }
        t += ts;
        xv0 = xv1; xv1 = pf;
        __syncthreads();
    }
}

// ======================= K3: emissions =======================
// grid SEQ, block 1024 = 128 b x 8 k. ft layout: [b][t][8] for streaming in K4.
template<typename HT>
__global__ __launch_bounds__(1024, 1)
void emis_kernel(const HT* __restrict__ hbuf, const float* __restrict__ W_out,
                 const float* __restrict__ b_out, float* __restrict__ ft)
{
    const int t = blockIdx.x;
    const int b = threadIdx.x >> 3;
    const int k = threadIdx.x & 7;
    const HT* __restrict__ hf = hbuf + (size_t)b * (SEQ * HD) + t * HD;
    const HT* __restrict__ hb = hbuf + (size_t)(BSZ + b) * (SEQ * HD) + t * HD;
    float v = 0.0f;
    if (k < NTAG) {
        const float* __restrict__ wk = W_out + k * 256;
        float a0 = 0.f, a1 = 0.f;
        #pragma unroll
        for (int u = 0; u < HD; u += 2) {
            a0 += ldf(&hf[u]) * wk[u]      + ldf(&hb[u])     * wk[HD + u];
            a1 += ldf(&hf[u + 1]) * wk[u + 1] + ldf(&hb[u + 1]) * wk[HD + u + 1];
        }
        v = a0 + a1 + b_out[k];
    }
    ft[(size_t)b * (SEQ * 8) + t * 8 + k] = v;
}

// ======================= K4: Viterbi scan + backtrace =======================
// grid BSZ, block 64 (one wave): lane = next*8 + prev.
__global__ __launch_bounds__(64, 1)
void vit_kernel(const float* __restrict__ ft, const float* __restrict__ trans,
                float* __restrict__ out)
{
    const int b = blockIdx.x;
    const int lane = threadIdx.x;
    __shared__ __align__(16) float ftl[SEQ * 8];
    __shared__ int bptr_lds[SEQ * 8];

    {   // stage this chain's emissions: 16 KB coalesced
        const float4* src = (const float4*)(ft + (size_t)b * (SEQ * 8));
        float4* dst = (float4*)ftl;
        #pragma unroll
        for (int i = 0; i < SEQ * 2 / 64; ++i) dst[lane + i * 64] = src[lane + i * 64];
    }
    __syncthreads();

    const int next = lane >> 3;
    const int prev = lane & 7;
    const bool pv = (prev < NTAG);
    const bool nv = (next < NTAG);
    const float trv = (pv && nv) ? trans[next * NTAG + prev] : -3.0e38f;
    float fvp = pv ? ((prev == BOSX) ? 0.0f : NEGC) : -3.0e38f;
    for (int t = 0; t < SEQ; ++t) {
        float m = fvp + trv;
        int am = prev;
        #pragma unroll
        for (int off = 1; off < 8; off <<= 1) {          // first-max-index semantics
            const float om = __shfl_xor(m, off);
            const int oa = __shfl_xor(am, off);
            if (om > m || (om == m && oa < am)) { m = om; am = oa; }
        }
        const float fvnew = m + ftl[t * 8 + next];
        if (prev == 0) bptr_lds[t * 8 + next] = am;
        fvp = __shfl(fvnew, prev << 3);
        if (!pv) fvp = -3.0e38f;
    }
    float term = pv ? (fvp + trans[EOSX * NTAG + prev]) : -3.0e38f;
    int am = prev;
    #pragma unroll
    for (int off = 1; off < 8; off <<= 1) {
        const float om = __shfl_xor(term, off);
        const int oa = __shfl_xor(am, off);
        if (om > term || (om == term && oa < am)) { term = om; am = oa; }
    }
    if (lane == 0) {
        out[b] = term;
        int cur = am;
        for (int t = SEQ - 1; t >= 0; --t) {
            out[BSZ + t * BSZ + b] = (float)cur;
            cur = bptr_lds[t * 8 + cur];
        }
    }
}

// ======================= launch =======================
template<typename XWT, typename HT>
static void run_all(const int* sen, const float* emb,
                    const float* Wih_f, const float* Whh_f, const float* b_f,
                    const float* Wih_b, const float* Whh_b, const float* b_b,
                    const float* W_out, const float* b_out, const float* trans,
                    XWT* xw, HT* hb, float* ft, float* out, hipStream_t stream)
{
    proj_kernel<XWT><<<dim3(2 * BSZ, SEQ / 64), dim3(1024), 0, stream>>>(
        sen, emb, Wih_f, b_f, Wih_b, b_b, xw);
    rec_kernel<XWT, HT><<<dim3(2 * BSZ), dim3(1024), 0, stream>>>(
        Whh_f, Whh_b, xw, hb);
    emis_kernel<HT><<<dim3(SEQ), dim3(1024), 0, stream>>>(hb, W_out, b_out, ft);
    vit_kernel<<<dim3(BSZ), dim3(64), 0, stream>>>(ft, trans, out);
}

extern "C" void kernel_launch(void* const* d_in, const int* in_sizes, int n_in,
                              void* d_out, int out_size, void* d_ws, size_t ws_size,
                              hipStream_t stream)
{
    const int*   sen   = (const int*)d_in[0];
    const float* emb   = (const float*)d_in[1];
    const float* Wih_f = (const float*)d_in[2];
    const float* Whh_f = (const float*)d_in[3];
    const float* b_f   = (const float*)d_in[4];
    const float* Wih_b = (const float*)d_in[5];
    const float* Whh_b = (const float*)d_in[6];
    const float* b_b   = (const float*)d_in[7];
    const float* W_out = (const float*)d_in[8];
    const float* b_out = (const float*)d_in[9];
    const float* trans = (const float*)d_in[10];
    float* out = (float*)d_out;

    char* ws = (char*)d_ws;
    const size_t xw_elems = (size_t)2 * BSZ * SEQ * H4;   // 67,108,864
    const size_t h_elems  = (size_t)2 * BSZ * SEQ * HD;   // 16,777,216
    const size_t ft_bytes = (size_t)BSZ * SEQ * 8 * 4;    // 2 MB

    if (ws_size >= xw_elems * 4 + h_elems * 4 + ft_bytes) {
        float* xw = (float*)ws;
        float* hb = (float*)(ws + xw_elems * 4);
        float* ft = (float*)(ws + xw_elems * 4 + h_elems * 4);
        run_all<float, float>(sen, emb, Wih_f, Whh_f, b_f, Wih_b, Whh_b, b_b,
                              W_out, b_out, trans, xw, hb, ft, out, stream);
    } else if (ws_size >= xw_elems * 2 + h_elems * 4 + ft_bytes) {
        __hip_bfloat16* xw = (__hip_bfloat16*)ws;
        float* hb = (float*)(ws + xw_elems * 2);
        float* ft = (float*)(ws + xw_elems * 2 + h_elems * 4);
        run_all<__hip_bfloat16, float>(sen, emb, Wih_f, Whh_f, b_f, Wih_b, Whh_b, b_b,
                                       W_out, b_out, trans, xw, hb, ft, out, stream);
    } else {
        __hip_bfloat16* xw = (__hip_bfloat16*)ws;
        __hip_bfloat16* hb = (__hip_bfloat16*)(ws + xw_elems * 2);
        float* ft = (float*)(ws + xw_elems * 2 + h_elems * 2);
        run_all<__hip_bfloat16, __hip_bfloat16>(sen, emb, Wih_f, Whh_f, b_f, Wih_b, Whh_b, b_b,
                                                W_out, b_out, trans, xw, hb, ft, out, stream);
    }
}

// Round 5
// 1425.263 us; speedup vs baseline: 2.9190x; 1.1594x over previous
//
#include <hip/hip_runtime.h>
#include <hip/hip_bf16.h>
#include <math.h>
#include <type_traits>

#define SEQ  512
#define BSZ  128
#define EMBD 128
#define H4   512
#define HD   128
#define NTAG 7
#define BOSX 4
#define EOSX 5
#define NEGC (-10000.0f)

typedef float v2f __attribute__((ext_vector_type(2)));

template<typename T> __device__ __forceinline__ float ldf(const T* p);
template<> __device__ __forceinline__ float ldf<float>(const float* p) { return *p; }
template<> __device__ __forceinline__ float ldf<__hip_bfloat16>(const __hip_bfloat16* p) { return __bfloat162float(*p); }
template<typename T> __device__ __forceinline__ void stf(T* p, float v);
template<> __device__ __forceinline__ void stf<float>(float* p, float v) { *p = v; }
template<> __device__ __forceinline__ void stf<__hip_bfloat16>(__hip_bfloat16* p, float v) { *p = __float2bfloat16(v); }

__device__ __forceinline__ float fast_sigmoid(float x) {
    return 1.0f / (1.0f + __expf(-x));            // -x large -> exp=inf -> 0: safe
}
__device__ __forceinline__ float fast_tanh(float x) {
    const float ax = fabsf(x);
    const float e = __expf(-2.0f * ax);           // in (0,1]: safe
    return copysignf((1.0f - e) / (1.0f + e), x);
}

// Skewed row stride: 128 floats stored as [0..63] + pad4 + [64..127] + pad4.
// half-1 base offset = 68 floats -> bank shift +4 vs half-0: for any k the two
// halves' b128 reads hit disjoint banks (R4: 1.34e8 conflict cycles from the
// unskewed half*64 layout).
#define RSTRIDE 136
#define HALF_OFF 68

// 32 packed-fp32 FMAs over one 64-float half-row held in v2f w2[32].
__device__ __forceinline__ float half_dot(const v2f* __restrict__ w2, const float4* __restrict__ hv)
{
    v2f a0 = {0.f, 0.f}, a1 = {0.f, 0.f}, a2 = {0.f, 0.f}, a3 = {0.f, 0.f};
    #pragma unroll
    for (int k = 0; k < 16; k += 2) {
        float4 h4 = hv[k];
        v2f lo; lo.x = h4.x; lo.y = h4.y;
        v2f hi; hi.x = h4.z; hi.y = h4.w;
        a0 = __builtin_elementwise_fma(w2[2 * k], lo, a0);
        a1 = __builtin_elementwise_fma(w2[2 * k + 1], hi, a1);
        h4 = hv[k + 1];
        lo.x = h4.x; lo.y = h4.y;
        hi.x = h4.z; hi.y = h4.w;
        a2 = __builtin_elementwise_fma(w2[2 * k + 2], lo, a2);
        a3 = __builtin_elementwise_fma(w2[2 * k + 3], hi, a3);
    }
    return ((a0.x + a0.y) + (a1.x + a1.y)) + ((a2.x + a2.y) + (a3.x + a3.y));
}

// ======================= K1: input projection =======================
// grid (2*BSZ, SEQ/64), block 1024 = 512 rows x 2 halves (64-float half-row in
// regs; 128-float rows spill at the compiler's 128-VGPR cap, see R2/R3).
template<typename XWT>
__global__ __launch_bounds__(1024, 1)
void proj_kernel(const int* __restrict__ sen, const float* __restrict__ emb,
                 const float* __restrict__ Wih_f, const float* __restrict__ b_f,
                 const float* __restrict__ Wih_b, const float* __restrict__ b_b,
                 XWT* __restrict__ xw)
{
    const int tid  = threadIdx.x;
    const int row  = tid >> 1;       // 0..511 gate row
    const int half = tid & 1;        // 0..1   K-half
    const int chain = blockIdx.x;
    const int dir = chain & 1;
    const int b = chain >> 1;
    const int t0 = blockIdx.y * 64;
    const float* __restrict__ Wih  = dir ? Wih_b : Wih_f;
    const float* __restrict__ bias = dir ? b_b : b_f;

    __shared__ __align__(16) float xs[32][RSTRIDE];   // 17 KB, skewed

    v2f w2[32];                                       // 64 VGPRs: half weight row
    {
        const float4* wr = (const float4*)(Wih + row * EMBD + half * 64);
        #pragma unroll
        for (int k = 0; k < 16; ++k) {
            const float4 f4 = wr[k];
            w2[2 * k].x = f4.x;     w2[2 * k].y = f4.y;
            w2[2 * k + 1].x = f4.z; w2[2 * k + 1].y = f4.w;
        }
    }
    const float bj = bias[row];
    XWT* __restrict__ xw_c = xw + (size_t)chain * (SEQ * H4);

    for (int tt = 0; tt < 64; tt += 32) {
        {   // stage 32 embedding rows (skewed): each thread moves one float4
            const int srow = tid >> 5;                 // 0..31
            const int col = tid & 31;                  // 0..31 float4s
            const int tok = sen[(t0 + tt + srow) * BSZ + b];
            const float4 v = ((const float4*)(emb + (size_t)tok * EMBD))[col];
            const int doff = (col < 16) ? (col * 4) : (HALF_OFF + (col - 16) * 4);
            *(float4*)(&xs[srow][doff]) = v;
        }
        __syncthreads();
        for (int i = 0; i < 32; ++i) {
            const float4* xv = (const float4*)(xs[i] + half * HALF_OFF);
            float tot = half_dot(w2, xv);
            tot += __shfl_xor(tot, 1);                 // combine the two halves
            if (half == 0)
                stf(&xw_c[(t0 + tt + i) * H4 + row], tot + bj);
        }
        __syncthreads();
    }
}

// ======================= K2: LSTM recurrence =======================
// grid 2*BSZ (1 block/CU), block 1024 = 128 u x 8 q, q = gate*2 + half.
// Each thread: half-dot for (gate, u). shfl_xor(1) combines halves; 4 in-wave
// shuffles gather the activated gates to q==0, which updates (c,h) locally.
// h double-buffered in skewed LDS -> ONE barrier per step (R4 had 2 barriers
// + gate_lds round-trip + 1.34e8 bank-conflict cycles).
template<typename XWT, typename HT>
__global__ __launch_bounds__(1024, 1)
void rec_kernel(const float* __restrict__ Whh_f, const float* __restrict__ Whh_b,
                const XWT* __restrict__ xw, HT* __restrict__ hbuf)
{
    const int tid  = threadIdx.x;
    const int u    = tid >> 3;        // 0..127 hidden index
    const int q    = tid & 7;
    const int g    = q >> 1;          // 0:i 1:f 2:g 3:o
    const int half = q & 1;
    const int lane = tid & 63;
    const int chain = blockIdx.x;
    const int dir = chain & 1;
    const int b = chain >> 1;
    const float* __restrict__ Whh = dir ? Whh_b : Whh_f;

    __shared__ __align__(16) float hdb[2][RSTRIDE];   // double-buffered, skewed

    v2f w2[32];                                       // 64 VGPRs: half weight row
    {
        const float4* wr = (const float4*)(Whh + (g * HD + u) * HD + half * 64);
        #pragma unroll
        for (int k = 0; k < 16; ++k) {
            const float4 f4 = wr[k];
            w2[2 * k].x = f4.x;     w2[2 * k].y = f4.y;
            w2[2 * k + 1].x = f4.z; w2[2 * k + 1].y = f4.w;
        }
    }
    if (tid < 2 * RSTRIDE) ((float*)hdb)[tid] = 0.0f;
    float c = 0.0f;
    const XWT* __restrict__ xw_c = xw + (size_t)chain * (SEQ * H4);
    HT* __restrict__ hb_c = hbuf + (size_t)(dir * BSZ + b) * (SEQ * HD);
    __syncthreads();

    int t = dir ? (SEQ - 1) : 0;
    const int ts = dir ? -1 : 1;
    // depth-2 xw prefetch, half-0 threads only (they finalize the gate)
    float xv0 = 0.f, xv1 = 0.f;
    if (half == 0) {
        xv0 = ldf(&xw_c[t * H4 + g * HD + u]);
        xv1 = ldf(&xw_c[(t + ts) * H4 + g * HD + u]);
    }
    const int base = lane & 56;                        // my u-group's lane 0
    for (int s = 0; s < SEQ; ++s) {
        float pf = 0.0f;
        if (half == 0 && s + 2 < SEQ) pf = ldf(&xw_c[(t + 2 * ts) * H4 + g * HD + u]);
        const float4* hv = (const float4*)(hdb[s & 1] + half * HALF_OFF);
        float tot = half_dot(w2, hv);
        tot += __shfl_xor(tot, 1);                     // full dot at even q
        float gate = 0.0f;
        if (half == 0) {
            const float z = tot + xv0;
            gate = (g == 2) ? fast_tanh(z) : fast_sigmoid(z);
        }
        const float gi = __shfl(gate, base + 0);
        const float gf = __shfl(gate, base + 2);
        const float gg = __shfl(gate, base + 4);
        const float go = __shfl(gate, base + 6);
        if (q == 0) {
            c = gf * c + gi * gg;
            const float h = go * fast_tanh(c);
            hdb[(s & 1) ^ 1][u + ((u >> 6) << 2)] = h; // skewed write
            stf(&hb_c[t * HD + u], h);
        }
        t += ts;
        xv0 = xv1; xv1 = pf;
        __syncthreads();
    }
}

// ======================= K3: emissions =======================
// grid SEQ, block 1024 = 128 b x 8 k. ft layout: [b][t][8] for streaming in K4.
template<typename HT>
__global__ __launch_bounds__(1024, 1)
void emis_kernel(const HT* __restrict__ hbuf, const float* __restrict__ W_out,
                 const float* __restrict__ b_out, float* __restrict__ ft)
{
    const int t = blockIdx.x;
    const int b = threadIdx.x >> 3;
    const int k = threadIdx.x & 7;
    const HT* __restrict__ hf = hbuf + (size_t)b * (SEQ * HD) + t * HD;
    const HT* __restrict__ hb = hbuf + (size_t)(BSZ + b) * (SEQ * HD) + t * HD;
    float v = 0.0f;
    if (k < NTAG) {
        const float* __restrict__ wk = W_out + k * 256;
        if constexpr (std::is_same_v<HT, float>) {
            const float4* hf4 = (const float4*)hf;
            const float4* hb4 = (const float4*)hb;
            const float4* wf4 = (const float4*)wk;
            const float4* wb4 = (const float4*)(wk + HD);
            float a0 = 0.f, a1 = 0.f, a2 = 0.f, a3 = 0.f;
            #pragma unroll
            for (int uq = 0; uq < 32; ++uq) {
                const float4 h4 = hf4[uq], w4 = wf4[uq];
                a0 += h4.x * w4.x + h4.y * w4.y;
                a1 += h4.z * w4.z + h4.w * w4.w;
                const float4 g4 = hb4[uq], x4 = wb4[uq];
                a2 += g4.x * x4.x + g4.y * x4.y;
                a3 += g4.z * x4.z + g4.w * x4.w;
            }
            v = (a0 + a1) + (a2 + a3) + b_out[k];
        } else {
            float a0 = 0.f, a1 = 0.f;
            #pragma unroll
            for (int uq = 0; uq < HD; uq += 2) {
                a0 += ldf(&hf[uq]) * wk[uq]         + ldf(&hb[uq])     * wk[HD + uq];
                a1 += ldf(&hf[uq + 1]) * wk[uq + 1] + ldf(&hb[uq + 1]) * wk[HD + uq + 1];
            }
            v = a0 + a1 + b_out[k];
        }
    }
    ft[(size_t)b * (SEQ * 8) + t * 8 + k] = v;
}

// ======================= K4: Viterbi scan + backtrace =======================
// grid BSZ, block 64 (one wave): lane = next*8 + prev.
__global__ __launch_bounds__(64, 1)
void vit_kernel(const float* __restrict__ ft, const float* __restrict__ trans,
                float* __restrict__ out)
{
    const int b = blockIdx.x;
    const int lane = threadIdx.x;
    __shared__ __align__(16) float ftl[SEQ * 8];
    __shared__ int bptr_lds[SEQ * 8];

    {   // stage this chain's emissions: 16 KB coalesced
        const float4* src = (const float4*)(ft + (size_t)b * (SEQ * 8));
        float4* dst = (float4*)ftl;
        #pragma unroll
        for (int i = 0; i < SEQ * 2 / 64; ++i) dst[lane + i * 64] = src[lane + i * 64];
    }
    __syncthreads();

    const int next = lane >> 3;
    const int prev = lane & 7;
    const bool pv = (prev < NTAG);
    const bool nv = (next < NTAG);
    const float trv = (pv && nv) ? trans[next * NTAG + prev] : -3.0e38f;
    float fvp = pv ? ((prev == BOSX) ? 0.0f : NEGC) : -3.0e38f;
    for (int t = 0; t < SEQ; ++t) {
        float m = fvp + trv;
        int am = prev;
        #pragma unroll
        for (int off = 1; off < 8; off <<= 1) {          // first-max-index semantics
            const float om = __shfl_xor(m, off);
            const int oa = __shfl_xor(am, off);
            if (om > m || (om == m && oa < am)) { m = om; am = oa; }
        }
        const float fvnew = m + ftl[t * 8 + next];
        if (prev == 0) bptr_lds[t * 8 + next] = am;
        fvp = __shfl(fvnew, prev << 3);
        if (!pv) fvp = -3.0e38f;
    }
    float term = pv ? (fvp + trans[EOSX * NTAG + prev]) : -3.0e38f;
    int am = prev;
    #pragma unroll
    for (int off = 1; off < 8; off <<= 1) {
        const float om = __shfl_xor(term, off);
        const int oa = __shfl_xor(am, off);
        if (om > term || (om == term && oa < am)) { term = om; am = oa; }
    }
    if (lane == 0) {
        out[b] = term;
        int cur = am;
        for (int t = SEQ - 1; t >= 0; --t) {
            out[BSZ + t * BSZ + b] = (float)cur;
            cur = bptr_lds[t * 8 + cur];
        }
    }
}

// ======================= launch =======================
template<typename XWT, typename HT>
static void run_all(const int* sen, const float* emb,
                    const float* Wih_f, const float* Whh_f, const float* b_f,
                    const float* Wih_b, const float* Whh_b, const float* b_b,
                    const float* W_out, const float* b_out, const float* trans,
                    XWT* xw, HT* hb, float* ft, float* out, hipStream_t stream)
{
    proj_kernel<XWT><<<dim3(2 * BSZ, SEQ / 64), dim3(1024), 0, stream>>>(
        sen, emb, Wih_f, b_f, Wih_b, b_b, xw);
    rec_kernel<XWT, HT><<<dim3(2 * BSZ), dim3(1024), 0, stream>>>(
        Whh_f, Whh_b, xw, hb);
    emis_kernel<HT><<<dim3(SEQ), dim3(1024), 0, stream>>>(hb, W_out, b_out, ft);
    vit_kernel<<<dim3(BSZ), dim3(64), 0, stream>>>(ft, trans, out);
}

extern "C" void kernel_launch(void* const* d_in, const int* in_sizes, int n_in,
                              void* d_out, int out_size, void* d_ws, size_t ws_size,
                              hipStream_t stream)
{
    const int*   sen   = (const int*)d_in[0];
    const float* emb   = (const float*)d_in[1];
    const float* Wih_f = (const float*)d_in[2];
    const float* Whh_f = (const float*)d_in[3];
    const float* b_f   = (const float*)d_in[4];
    const float* Wih_b = (const float*)d_in[5];
    const float* Whh_b = (const float*)d_in[6];
    const float* b_b   = (const float*)d_in[7];
    const float* W_out = (const float*)d_in[8];
    const float* b_out = (const float*)d_in[9];
    const float* trans = (const float*)d_in[10];
    float* out = (float*)d_out;

    char* ws = (char*)d_ws;
    const size_t xw_elems = (size_t)2 * BSZ * SEQ * H4;   // 67,108,864
    const size_t h_elems  = (size_t)2 * BSZ * SEQ * HD;   // 16,777,216
    const size_t ft_bytes = (size_t)BSZ * SEQ * 8 * 4;    // 2 MB

    if (ws_size >= xw_elems * 4 + h_elems * 4 + ft_bytes) {
        float* xw = (float*)ws;
        float* hb = (float*)(ws + xw_elems * 4);
        float* ft = (float*)(ws + xw_elems * 4 + h_elems * 4);
        run_all<float, float>(sen, emb, Wih_f, Whh_f, b_f, Wih_b, Whh_b, b_b,
                              W_out, b_out, trans, xw, hb, ft, out, stream);
    } else if (ws_size >= xw_elems * 2 + h_elems * 4 + ft_bytes) {
        __hip_bfloat16* xw = (__hip_bfloat16*)ws;
        float* hb = (float*)(ws + xw_elems * 2);
        float* ft = (float*)(ws + xw_elems * 2 + h_elems * 4);
        run_all<__hip_bfloat16, float>(sen, emb, Wih_f, Whh_f, b_f, Wih_b, Whh_b, b_b,
                                       W_out, b_out, trans, xw, hb, ft, out, stream);
    } else {
        __hip_bfloat16* xw = (__hip_bfloat16*)ws;
        __hip_bfloat16* hb = (__hip_bfloat16*)(ws + xw_elems * 2);
        float* ft = (float*)(ws + xw_elems * 2 + h_elems * 2);
        run_all<__hip_bfloat16, __hip_bfloat16>(sen, emb, Wih_f, Whh_f, b_f, Wih_b, Whh_b, b_b,
                                                W_out, b_out, trans, xw, hb, ft, out, stream);
    }
}

// Round 6
// 1403.860 us; speedup vs baseline: 2.9635x; 1.0152x over previous
//
#include <hip/hip_runtime.h>
#include <hip/hip_bf16.h>
#include <math.h>
#include <type_traits>

#define SEQ  512
#define BSZ  128
#define EMBD 128
#define H4   512
#define HD   128
#define NTAG 7
#define BOSX 4
#define EOSX 5
#define NEGC (-10000.0f)

typedef float v2f __attribute__((ext_vector_type(2)));

template<typename T> __device__ __forceinline__ float ldf(const T* p);
template<> __device__ __forceinline__ float ldf<float>(const float* p) { return *p; }
template<> __device__ __forceinline__ float ldf<__hip_bfloat16>(const __hip_bfloat16* p) { return __bfloat162float(*p); }
template<typename T> __device__ __forceinline__ void stf(T* p, float v);
template<> __device__ __forceinline__ void stf<float>(float* p, float v) { *p = v; }
template<> __device__ __forceinline__ void stf<__hip_bfloat16>(__hip_bfloat16* p, float v) { *p = __float2bfloat16(v); }

template<typename T> __device__ __forceinline__ float4 ld4(const T* p);
template<> __device__ __forceinline__ float4 ld4<float>(const float* p) { return *(const float4*)p; }
template<> __device__ __forceinline__ float4 ld4<__hip_bfloat16>(const __hip_bfloat16* p) {
    float4 r; r.x = __bfloat162float(p[0]); r.y = __bfloat162float(p[1]);
    r.z = __bfloat162float(p[2]); r.w = __bfloat162float(p[3]); return r;
}
template<typename T> __device__ __forceinline__ void st4(T* p, float4 v);
template<> __device__ __forceinline__ void st4<float>(float* p, float4 v) { *(float4*)p = v; }
template<> __device__ __forceinline__ void st4<__hip_bfloat16>(__hip_bfloat16* p, float4 v) {
    p[0] = __float2bfloat16(v.x); p[1] = __float2bfloat16(v.y);
    p[2] = __float2bfloat16(v.z); p[3] = __float2bfloat16(v.w);
}

__device__ __forceinline__ float fast_sigmoid(float x) {
    return 1.0f / (1.0f + __expf(-x));            // -x large -> exp=inf -> 0: safe
}
__device__ __forceinline__ float fast_tanh(float x) {
    const float ax = fabsf(x);
    const float e = __expf(-2.0f * ax);           // in (0,1]: safe
    return copysignf((1.0f - e) / (1.0f + e), x);
}

// k lives in lane bits {0,1,3}: full k-reduction in DPP (VALU pipe) — R5 showed
// __shfl = ds_bpermute shares the LDS pipe that is the bottleneck.
template<int C> __device__ __forceinline__ float dppadd(float x) {
    const int y = __builtin_amdgcn_update_dpp(0, __builtin_bit_cast(int, x), C, 0xF, 0xF, true);
    return x + __builtin_bit_cast(float, y);
}
__device__ __forceinline__ float kreduce(float x) {
    x = dppadd<0xB1>(x);    // quad_perm [1,0,3,2]  : xor lane bit0 (k bit0)
    x = dppadd<0x4E>(x);    // quad_perm [2,3,0,1]  : xor lane bit1 (k bit1)
    x = dppadd<0x128>(x);   // row_ror:8            : xor lane bit3 (k bit2)
    return x;
}

// Chunked-skew LDS layout: chunk k (16 floats) at float offset 20*k.
// k*20 mod 32 = {0,20,8,28,16,4,24,12} -> one b128 per chunk covers all 32
// banks exactly once across the wave's 8 distinct chunk addresses.
#define CHUNK_STRIDE 20
#define ROW_STRIDE 160          // 8 chunks * 20
__device__ __forceinline__ int hoff(int u) { return (u >> 4) * CHUNK_STRIDE + (u & 15); }

// 16-float chunk dot: w2 = 8 v2f (packed fp32), r = 4 float4 of the chunk.
__device__ __forceinline__ float dot16(const v2f* __restrict__ w2, const float4* __restrict__ r) {
    v2f a = {0.f, 0.f};
    #pragma unroll
    for (int j = 0; j < 4; ++j) {
        v2f lo; lo.x = r[j].x; lo.y = r[j].y;
        v2f hi; hi.x = r[j].z; hi.y = r[j].w;
        a = __builtin_elementwise_fma(w2[2 * j], lo, a);
        a = __builtin_elementwise_fma(w2[2 * j + 1], hi, a);
    }
    return a.x + a.y;
}

// ======================= K1: input projection =======================
// grid (2*BSZ, SEQ/64), block 1024 = 128 u x 8 k. Thread (u,k) computes all 4
// gates of unit u over x-chunk k: 4 b128 LDS reads per t (R5: 16), weights
// 4x16=64 floats in VGPRs. xw layout: [t][u][4 gates] (float4 for rec).
template<typename XWT>
__global__ __launch_bounds__(1024, 1)
void proj_kernel(const int* __restrict__ sen, const float* __restrict__ emb,
                 const float* __restrict__ Wih_f, const float* __restrict__ b_f,
                 const float* __restrict__ Wih_b, const float* __restrict__ b_b,
                 XWT* __restrict__ xw)
{
    const int tid = threadIdx.x;
    const int wid = tid >> 6;
    const int lane = tid & 63;
    const int k = (lane & 3) | ((lane >> 1) & 4);          // lane bits 0,1,3
    const int m = ((lane >> 2) & 1) | ((lane >> 3) & 6);   // lane bits 2,4,5
    const int u = wid * 8 + m;
    const int chain = blockIdx.x;
    const int dir = chain & 1;
    const int b = chain >> 1;
    const int t0 = blockIdx.y * 64;
    const float* __restrict__ Wih  = dir ? Wih_b : Wih_f;
    const float* __restrict__ bias = dir ? b_b : b_f;

    __shared__ __align__(16) float xs[32 * ROW_STRIDE];    // 20 KB, chunk-skewed

    v2f w2[4][8];                                          // 64 VGPRs: 4 gate rows x chunk k
    float4 bj;
    {
        #pragma unroll
        for (int g = 0; g < 4; ++g) {
            const float4* wr = (const float4*)(Wih + (g * HD + u) * EMBD + k * 16);
            #pragma unroll
            for (int j = 0; j < 4; ++j) {
                const float4 f4 = wr[j];
                w2[g][2 * j].x = f4.x;     w2[g][2 * j].y = f4.y;
                w2[g][2 * j + 1].x = f4.z; w2[g][2 * j + 1].y = f4.w;
            }
        }
        bj.x = bias[u]; bj.y = bias[HD + u]; bj.z = bias[2 * HD + u]; bj.w = bias[3 * HD + u];
    }
    XWT* __restrict__ xw_c = xw + (size_t)chain * (SEQ * H4);

    for (int tt = 0; tt < 64; tt += 32) {
        {   // stage 32 embedding rows into chunk-skewed layout
            const int srow = tid >> 5;                     // 0..31
            const int col = tid & 31;                      // float4 index 0..31
            const int tok = sen[(t0 + tt + srow) * BSZ + b];
            const float4 v = ((const float4*)(emb + (size_t)tok * EMBD))[col];
            *(float4*)(&xs[srow * ROW_STRIDE + (col >> 2) * CHUNK_STRIDE + (col & 3) * 4]) = v;
        }
        __syncthreads();
        for (int i = 0; i < 32; ++i) {
            const float4* xr = (const float4*)(xs + i * ROW_STRIDE + k * CHUNK_STRIDE);
            float4 r[4];
            #pragma unroll
            for (int j = 0; j < 4; ++j) r[j] = xr[j];
            float z0 = kreduce(dot16(w2[0], r));
            float z1 = kreduce(dot16(w2[1], r));
            float z2 = kreduce(dot16(w2[2], r));
            float z3 = kreduce(dot16(w2[3], r));
            if (k == 0) {
                float4 o; o.x = z0 + bj.x; o.y = z1 + bj.y; o.z = z2 + bj.z; o.w = z3 + bj.w;
                st4(&xw_c[(t0 + tt + i) * H4 + u * 4], o);
            }
        }
        __syncthreads();
    }
}

// ======================= K2: LSTM recurrence =======================
// grid 2*BSZ (1 block/CU), block 1024 = 128 u x 8 k. Same decomposition as K1;
// h double-buffered in chunk-skewed LDS. DPP k-reduce leaves the full 4 gates
// in EVERY lane -> all 8 k-lanes of a u redundantly compute (c,h) (keeps c in
// regs, no gather shuffles, no divergence); k==0 writes h. 1 barrier/step.
template<typename XWT, typename HT>
__global__ __launch_bounds__(1024, 1)
void rec_kernel(const float* __restrict__ Whh_f, const float* __restrict__ Whh_b,
                const XWT* __restrict__ xw, HT* __restrict__ hbuf)
{
    const int tid = threadIdx.x;
    const int wid = tid >> 6;
    const int lane = tid & 63;
    const int k = (lane & 3) | ((lane >> 1) & 4);
    const int m = ((lane >> 2) & 1) | ((lane >> 3) & 6);
    const int u = wid * 8 + m;
    const int chain = blockIdx.x;
    const int dir = chain & 1;
    const int b = chain >> 1;
    const float* __restrict__ Whh = dir ? Whh_b : Whh_f;

    __shared__ __align__(16) float hdb[2][ROW_STRIDE];     // double-buffered, chunk-skewed

    v2f w2[4][8];                                          // 64 VGPRs
    #pragma unroll
    for (int g = 0; g < 4; ++g) {
        const float4* wr = (const float4*)(Whh + (g * HD + u) * HD + k * 16);
        #pragma unroll
        for (int j = 0; j < 4; ++j) {
            const float4 f4 = wr[j];
            w2[g][2 * j].x = f4.x;     w2[g][2 * j].y = f4.y;
            w2[g][2 * j + 1].x = f4.z; w2[g][2 * j + 1].y = f4.w;
        }
    }
    if (tid < 2 * ROW_STRIDE) ((float*)hdb)[tid] = 0.0f;
    float c = 0.0f;
    const XWT* __restrict__ xw_c = xw + (size_t)chain * (SEQ * H4);
    HT* __restrict__ hb_c = hbuf + (size_t)(dir * BSZ + b) * (SEQ * HD);
    __syncthreads();

    int t = dir ? (SEQ - 1) : 0;
    const int ts = dir ? -1 : 1;
    // depth-2 xw prefetch; all k-lanes load the same float4 (coalescer merges)
    float4 xv0 = ld4(&xw_c[t * H4 + u * 4]);
    float4 xv1 = ld4(&xw_c[(t + ts) * H4 + u * 4]);
    const int woff = hoff(u);
    for (int s = 0; s < SEQ; ++s) {
        float4 pf = {0.f, 0.f, 0.f, 0.f};
        if (s + 2 < SEQ) pf = ld4(&xw_c[(t + 2 * ts) * H4 + u * 4]);
        const float4* hr = (const float4*)(hdb[s & 1] + k * CHUNK_STRIDE);
        float4 r[4];
        #pragma unroll
        for (int j = 0; j < 4; ++j) r[j] = hr[j];
        const float zi = kreduce(dot16(w2[0], r)) + xv0.x;
        const float zf = kreduce(dot16(w2[1], r)) + xv0.y;
        const float zg = kreduce(dot16(w2[2], r)) + xv0.z;
        const float zo = kreduce(dot16(w2[3], r)) + xv0.w;
        const float gi = fast_sigmoid(zi);
        const float gf = fast_sigmoid(zf);
        const float gg = fast_tanh(zg);
        const float go = fast_sigmoid(zo);
        c = gf * c + gi * gg;                              // redundant across the 8 k-lanes
        const float h = go * fast_tanh(c);
        if (k == 0) {
            hdb[(s & 1) ^ 1][woff] = h;
            stf(&hb_c[t * HD + u], h);
        }
        t += ts;
        xv0 = xv1; xv1 = pf;
        __syncthreads();
    }
}

// ======================= K3: emissions =======================
// grid SEQ, block 1024 = 128 b x 8 k. ft layout: [b][t][8] for streaming in K4.
template<typename HT>
__global__ __launch_bounds__(1024, 1)
void emis_kernel(const HT* __restrict__ hbuf, const float* __restrict__ W_out,
                 const float* __restrict__ b_out, float* __restrict__ ft)
{
    const int t = blockIdx.x;
    const int b = threadIdx.x >> 3;
    const int k = threadIdx.x & 7;
    const HT* __restrict__ hf = hbuf + (size_t)b * (SEQ * HD) + t * HD;
    const HT* __restrict__ hb = hbuf + (size_t)(BSZ + b) * (SEQ * HD) + t * HD;
    float v = 0.0f;
    if (k < NTAG) {
        const float* __restrict__ wk = W_out + k * 256;
        if constexpr (std::is_same_v<HT, float>) {
            const float4* hf4 = (const float4*)hf;
            const float4* hb4 = (const float4*)hb;
            const float4* wf4 = (const float4*)wk;
            const float4* wb4 = (const float4*)(wk + HD);
            float a0 = 0.f, a1 = 0.f, a2 = 0.f, a3 = 0.f;
            #pragma unroll
            for (int uq = 0; uq < 32; ++uq) {
                const float4 h4 = hf4[uq], w4 = wf4[uq];
                a0 += h4.x * w4.x + h4.y * w4.y;
                a1 += h4.z * w4.z + h4.w * w4.w;
                const float4 g4 = hb4[uq], x4 = wb4[uq];
                a2 += g4.x * x4.x + g4.y * x4.y;
                a3 += g4.z * x4.z + g4.w * x4.w;
            }
            v = (a0 + a1) + (a2 + a3) + b_out[k];
        } else {
            float a0 = 0.f, a1 = 0.f;
            #pragma unroll
            for (int uq = 0; uq < HD; uq += 2) {
                a0 += ldf(&hf[uq]) * wk[uq]         + ldf(&hb[uq])     * wk[HD + uq];
                a1 += ldf(&hf[uq + 1]) * wk[uq + 1] + ldf(&hb[uq + 1]) * wk[HD + uq + 1];
            }
            v = a0 + a1 + b_out[k];
        }
    }
    ft[(size_t)b * (SEQ * 8) + t * 8 + k] = v;
}

// ======================= K4: Viterbi scan + backtrace =======================
// grid BSZ, block 64 (one wave): lane = next*8 + prev.
__global__ __launch_bounds__(64, 1)
void vit_kernel(const float* __restrict__ ft, const float* __restrict__ trans,
                float* __restrict__ out)
{
    const int b = blockIdx.x;
    const int lane = threadIdx.x;
    __shared__ __align__(16) float ftl[SEQ * 8];
    __shared__ int bptr_lds[SEQ * 8];

    {   // stage this chain's emissions: 16 KB coalesced
        const float4* src = (const float4*)(ft + (size_t)b * (SEQ * 8));
        float4* dst = (float4*)ftl;
        #pragma unroll
        for (int i = 0; i < SEQ * 2 / 64; ++i) dst[lane + i * 64] = src[lane + i * 64];
    }
    __syncthreads();

    const int next = lane >> 3;
    const int prev = lane & 7;
    const bool pv = (prev < NTAG);
    const bool nv = (next < NTAG);
    const float trv = (pv && nv) ? trans[next * NTAG + prev] : -3.0e38f;
    float fvp = pv ? ((prev == BOSX) ? 0.0f : NEGC) : -3.0e38f;
    for (int t = 0; t < SEQ; ++t) {
        float m = fvp + trv;
        int am = prev;
        #pragma unroll
        for (int off = 1; off < 8; off <<= 1) {          // first-max-index semantics
            const float om = __shfl_xor(m, off);
            const int oa = __shfl_xor(am, off);
            if (om > m || (om == m && oa < am)) { m = om; am = oa; }
        }
        const float fvnew = m + ftl[t * 8 + next];
        if (prev == 0) bptr_lds[t * 8 + next] = am;
        fvp = __shfl(fvnew, prev << 3);
        if (!pv) fvp = -3.0e38f;
    }
    float term = pv ? (fvp + trans[EOSX * NTAG + prev]) : -3.0e38f;
    int am = prev;
    #pragma unroll
    for (int off = 1; off < 8; off <<= 1) {
        const float om = __shfl_xor(term, off);
        const int oa = __shfl_xor(am, off);
        if (om > term || (om == term && oa < am)) { term = om; am = oa; }
    }
    if (lane == 0) {
        out[b] = term;
        int cur = am;
        for (int t = SEQ - 1; t >= 0; --t) {
            out[BSZ + t * BSZ + b] = (float)cur;
            cur = bptr_lds[t * 8 + cur];
        }
    }
}

// ======================= launch =======================
template<typename XWT, typename HT>
static void run_all(const int* sen, const float* emb,
                    const float* Wih_f, const float* Whh_f, const float* b_f,
                    const float* Wih_b, const float* Whh_b, const float* b_b,
                    const float* W_out, const float* b_out, const float* trans,
                    XWT* xw, HT* hb, float* ft, float* out, hipStream_t stream)
{
    proj_kernel<XWT><<<dim3(2 * BSZ, SEQ / 64), dim3(1024), 0, stream>>>(
        sen, emb, Wih_f, b_f, Wih_b, b_b, xw);
    rec_kernel<XWT, HT><<<dim3(2 * BSZ), dim3(1024), 0, stream>>>(
        Whh_f, Whh_b, xw, hb);
    emis_kernel<HT><<<dim3(SEQ), dim3(1024), 0, stream>>>(hb, W_out, b_out, ft);
    vit_kernel<<<dim3(BSZ), dim3(64), 0, stream>>>(ft, trans, out);
}

extern "C" void kernel_launch(void* const* d_in, const int* in_sizes, int n_in,
                              void* d_out, int out_size, void* d_ws, size_t ws_size,
                              hipStream_t stream)
{
    const int*   sen   = (const int*)d_in[0];
    const float* emb   = (const float*)d_in[1];
    const float* Wih_f = (const float*)d_in[2];
    const float* Whh_f = (const float*)d_in[3];
    const float* b_f   = (const float*)d_in[4];
    const float* Wih_b = (const float*)d_in[5];
    const float* Whh_b = (const float*)d_in[6];
    const float* b_b   = (const float*)d_in[7];
    const float* W_out = (const float*)d_in[8];
    const float* b_out = (const float*)d_in[9];
    const float* trans = (const float*)d_in[10];
    float* out = (float*)d_out;

    char* ws = (char*)d_ws;
    const size_t xw_elems = (size_t)2 * BSZ * SEQ * H4;   // 67,108,864
    const size_t h_elems  = (size_t)2 * BSZ * SEQ * HD;   // 16,777,216
    const size_t ft_bytes = (size_t)BSZ * SEQ * 8 * 4;    // 2 MB

    if (ws_size >= xw_elems * 4 + h_elems * 4 + ft_bytes) {
        float* xw = (float*)ws;
        float* hb = (float*)(ws + xw_elems * 4);
        float* ft = (float*)(ws + xw_elems * 4 + h_elems * 4);
        run_all<float, float>(sen, emb, Wih_f, Whh_f, b_f, Wih_b, Whh_b, b_b,
                              W_out, b_out, trans, xw, hb, ft, out, stream);
    } else if (ws_size >= xw_elems * 2 + h_elems * 4 + ft_bytes) {
        __hip_bfloat16* xw = (__hip_bfloat16*)ws;
        float* hb = (float*)(ws + xw_elems * 2);
        float* ft = (float*)(ws + xw_elems * 2 + h_elems * 4);
        run_all<__hip_bfloat16, float>(sen, emb, Wih_f, Whh_f, b_f, Wih_b, Whh_b, b_b,
                                       W_out, b_out, trans, xw, hb, ft, out, stream);
    } else {
        __hip_bfloat16* xw = (__hip_bfloat16*)ws;
        __hip_bfloat16* hb = (__hip_bfloat16*)(ws + xw_elems * 2);
        float* ft = (float*)(ws + xw_elems * 2 + h_elems * 2);
        run_all<__hip_bfloat16, __hip_bfloat16>(sen, emb, Wih_f, Whh_f, b_f, Wih_b, Whh_b, b_b,
                                                W_out, b_out, trans, xw, hb, ft, out, stream);
    }
}

// Round 7
// 1196.401 us; speedup vs baseline: 3.4774x; 1.1734x over previous
//
#include <hip/hip_runtime.h>
#include <hip/hip_bf16.h>
#include <math.h>
#include <type_traits>

#define SEQ  512
#define BSZ  128
#define EMBD 128
#define H4   512
#define HD   128
#define NTAG 7
#define BOSX 4
#define EOSX 5
#define NEGC (-10000.0f)
#define TILE 16

typedef float v2f __attribute__((ext_vector_type(2)));

template<typename T> __device__ __forceinline__ void stf(T* p, float v);
template<> __device__ __forceinline__ void stf<float>(float* p, float v) { *p = v; }
template<> __device__ __forceinline__ void stf<__hip_bfloat16>(__hip_bfloat16* p, float v) { *p = __float2bfloat16(v); }
template<typename T> __device__ __forceinline__ void st4(T* p, float4 v);
template<> __device__ __forceinline__ void st4<float>(float* p, float4 v) { *(float4*)p = v; }
template<> __device__ __forceinline__ void st4<__hip_bfloat16>(__hip_bfloat16* p, float4 v) {
    p[0] = __float2bfloat16(v.x); p[1] = __float2bfloat16(v.y);
    p[2] = __float2bfloat16(v.z); p[3] = __float2bfloat16(v.w);
}

__device__ __forceinline__ float fast_sigmoid(float x) {
    return 1.0f / (1.0f + __expf(-x));            // -x large -> exp=inf -> 0: safe
}
__device__ __forceinline__ float fast_tanh(float x) {
    const float ax = fabsf(x);
    const float e = __expf(-2.0f * ax);           // in (0,1]: safe
    return copysignf((1.0f - e) / (1.0f + e), x);
}

// k lives in lane bits {0,1,3}: k-reduction entirely in DPP (VALU pipe).
template<int C> __device__ __forceinline__ float dppadd(float x) {
    const int y = __builtin_amdgcn_update_dpp(0, __builtin_bit_cast(int, x), C, 0xF, 0xF, true);
    return x + __builtin_bit_cast(float, y);
}
__device__ __forceinline__ float kreduce(float x) {
    x = dppadd<0xB1>(x);    // quad_perm [1,0,3,2]  : xor lane bit0
    x = dppadd<0x4E>(x);    // quad_perm [2,3,0,1]  : xor lane bit1
    x = dppadd<0x128>(x);   // row_ror:8            : xor lane bit3
    return x;
}

// Chunked-skew LDS layout for h: chunk k (16 floats) at float offset 20*k ->
// the wave's 8 distinct chunk b128s cover all 32 banks exactly once.
#define CHUNK_STRIDE 20
#define ROW_STRIDE 160
__device__ __forceinline__ int hoff(int u) { return (u >> 4) * CHUNK_STRIDE + (u & 15); }

// 16-float chunk dot: w2 = 8 v2f (packed fp32), r = 4 float4 of the chunk.
__device__ __forceinline__ float dot16(const v2f* __restrict__ w2, const float4* __restrict__ r) {
    v2f a = {0.f, 0.f};
    #pragma unroll
    for (int j = 0; j < 4; ++j) {
        v2f lo; lo.x = r[j].x; lo.y = r[j].y;
        v2f hi; hi.x = r[j].z; hi.y = r[j].w;
        a = __builtin_elementwise_fma(w2[2 * j], lo, a);
        a = __builtin_elementwise_fma(w2[2 * j + 1], hi, a);
    }
    return a.x + a.y;
}
__device__ __forceinline__ void ldw2(v2f* w2, const float4* wr) {
    #pragma unroll
    for (int j = 0; j < 4; ++j) {
        const float4 f4 = wr[j];
        w2[2 * j].x = f4.x;     w2[2 * j].y = f4.y;
        w2[2 * j + 1].x = f4.z; w2[2 * j + 1].y = f4.w;
    }
}

// ======================= K1: input projection =======================
// grid (2*BSZ, 2), block 1024 = 128 u x 8 k. Thread (u,k) computes all 4 gates
// of unit u over x-chunk k. xw layout: [t][u][4 gates].
template<typename XWT>
__global__ __launch_bounds__(1024, 1)
void proj_kernel(const int* __restrict__ sen, const float* __restrict__ emb,
                 const float* __restrict__ Wih_f, const float* __restrict__ b_f,
                 const float* __restrict__ Wih_b, const float* __restrict__ b_b,
                 XWT* __restrict__ xw)
{
    const int tid = threadIdx.x;
    const int wid = tid >> 6;
    const int lane = tid & 63;
    const int k = (lane & 3) | ((lane >> 1) & 4);          // lane bits 0,1,3
    const int m = ((lane >> 2) & 1) | ((lane >> 3) & 6);   // lane bits 2,4,5
    const int u = wid * 8 + m;
    const int chain = blockIdx.x;
    const int dir = chain & 1;
    const int b = chain >> 1;
    const int t0 = blockIdx.y * (SEQ / 2);
    const float* __restrict__ Wih  = dir ? Wih_b : Wih_f;
    const float* __restrict__ bias = dir ? b_b : b_f;

    __shared__ __align__(16) float xs[32 * ROW_STRIDE];    // 20 KB, chunk-skewed

    v2f w2[4][8];                                          // 64 VGPRs
    float4 bj;
    #pragma unroll
    for (int g = 0; g < 4; ++g)
        ldw2(w2[g], (const float4*)(Wih + (g * HD + u) * EMBD + k * 16));
    bj.x = bias[u]; bj.y = bias[HD + u]; bj.z = bias[2 * HD + u]; bj.w = bias[3 * HD + u];
    XWT* __restrict__ xw_c = xw + (size_t)chain * (SEQ * H4);

    for (int tt = 0; tt < SEQ / 2; tt += 32) {
        {   // stage 32 embedding rows into chunk-skewed layout
            const int srow = tid >> 5;
            const int col = tid & 31;
            const int tok = sen[(t0 + tt + srow) * BSZ + b];
            const float4 v = ((const float4*)(emb + (size_t)tok * EMBD))[col];
            *(float4*)(&xs[srow * ROW_STRIDE + (col >> 2) * CHUNK_STRIDE + (col & 3) * 4]) = v;
        }
        __syncthreads();
        for (int i = 0; i < 32; ++i) {
            const float4* xr = (const float4*)(xs + i * ROW_STRIDE + k * CHUNK_STRIDE);
            float4 r[4];
            #pragma unroll
            for (int j = 0; j < 4; ++j) r[j] = xr[j];
            const float z0 = kreduce(dot16(w2[0], r));
            const float z1 = kreduce(dot16(w2[1], r));
            const float z2 = kreduce(dot16(w2[2], r));
            const float z3 = kreduce(dot16(w2[3], r));
            if (k == 0) {
                float4 o; o.x = z0 + bj.x; o.y = z1 + bj.y; o.z = z2 + bj.z; o.w = z3 + bj.w;
                st4(&xw_c[(t0 + tt + i) * H4 + u * 4], o);
            }
        }
        __syncthreads();
    }
}

// ======================= K2: LSTM recurrence + fused emissions ==============
// grid 2*BSZ (1 block/CU), block 1024 = 128 u x 8 k.
// Steady-state step touches NO global memory (R4-R6 post-mortem: __syncthreads
// = s_waitcnt vmcnt(0)+s_barrier drained the per-step xw load + h store every
// step -> invariant ~3800 cyc/step). xw comes from a 16-step LDS tile staged
// once per 16 iters; h lives only in LDS; emissions (h . W_out) are computed
// by wave 0 from the h chunks it already reads, retained in registers, and
// flushed 112 dwords per 16 steps. hbuf + emis_kernel are gone entirely.
template<typename XWT>
__global__ __launch_bounds__(1024, 1)
void rec_kernel(const float* __restrict__ Whh_f, const float* __restrict__ Whh_b,
                const float* __restrict__ W_out,
                const XWT* __restrict__ xw,
                float* __restrict__ eft, float* __restrict__ ebt)
{
    const int tid = threadIdx.x;
    const int wid = tid >> 6;
    const int lane = tid & 63;
    const int k = (lane & 3) | ((lane >> 1) & 4);
    const int m = ((lane >> 2) & 1) | ((lane >> 3) & 6);
    const int u = wid * 8 + m;
    const int chain = blockIdx.x;
    const int dir = chain & 1;
    const int b = chain >> 1;
    const float* __restrict__ Whh = dir ? Whh_b : Whh_f;

    __shared__ __align__(16) float hdb[2][ROW_STRIDE];     // h double-buffer, chunk-skewed
    __shared__ __align__(16) float xwt[TILE][H4];          // 32 KB xw tile

    v2f w2[4][8];                                          // 64 VGPRs
    #pragma unroll
    for (int g = 0; g < 4; ++g)
        ldw2(w2[g], (const float4*)(Whh + (g * HD + u) * HD + k * 16));
    v2f wo[8];                                             // wave-0 emission weights
    {
        const int mm = (m < NTAG) ? m : 0;
        ldw2(wo, (const float4*)(W_out + mm * 256 + dir * HD + k * 16));
    }
    if (tid < 2 * ROW_STRIDE) ((float*)hdb)[tid] = 0.0f;
    float c = 0.0f, v0 = 0.0f, v1 = 0.0f;
    const XWT* __restrict__ xw_c = xw + (size_t)chain * (SEQ * H4);
    float* __restrict__ eX = (dir ? ebt : eft) + (size_t)b * (SEQ * 8);
    __syncthreads();

    const int t0 = dir ? (SEQ - 1) : 0;
    const int ts = dir ? -1 : 1;
    for (int s = 0; s <= SEQ; ++s) {
        if ((s & (TILE - 1)) == 0) {
            if (s < SEQ) {                                 // stage xw for steps s..s+15
                const int tg = t0 + ts * (s + wid);        // wave wid stages slot wid
                float4* dst = (float4*)xwt[wid];
                if constexpr (std::is_same_v<XWT, float>) {
                    const float4* src = (const float4*)(xw_c + tg * H4);
                    dst[lane] = src[lane];
                    dst[lane + 64] = src[lane + 64];
                } else {
                    const uint4 raw = ((const uint4*)(xw_c + tg * H4))[lane];  // 8 bf16
                    const unsigned rr[4] = {raw.x, raw.y, raw.z, raw.w};
                    float4 lo4, hi4;
                    float* lp = (float*)&lo4; float* hp = (float*)&hi4;
                    #pragma unroll
                    for (int j = 0; j < 2; ++j) {
                        lp[2*j]   = __builtin_bit_cast(float, rr[j] << 16);
                        lp[2*j+1] = __builtin_bit_cast(float, rr[j] & 0xFFFF0000u);
                        hp[2*j]   = __builtin_bit_cast(float, rr[j+2] << 16);
                        hp[2*j+1] = __builtin_bit_cast(float, rr[j+2] & 0xFFFF0000u);
                    }
                    dst[2 * lane] = lo4;
                    dst[2 * lane + 1] = hi4;
                }
            }
            __syncthreads();
        }
        const int cur = s & 1;
        float4 r[4];                                       // chunk k of h_{t-ts}
        {
            const float4* hr = (const float4*)(hdb[cur] + k * CHUNK_STRIDE);
            #pragma unroll
            for (int j = 0; j < 4; ++j) r[j] = hr[j];
        }
        if (s < SEQ) {
            const float4 xv = *(const float4*)(&xwt[s & (TILE - 1)][u * 4]);
            const float zi = kreduce(dot16(w2[0], r)) + xv.x;
            const float zf = kreduce(dot16(w2[1], r)) + xv.y;
            const float zg = kreduce(dot16(w2[2], r)) + xv.z;
            const float zo = kreduce(dot16(w2[3], r)) + xv.w;
            const float gi = fast_sigmoid(zi);
            const float gf = fast_sigmoid(zf);
            const float gg = fast_tanh(zg);
            const float go = fast_sigmoid(zo);
            c = gf * c + gi * gg;                          // redundant across k-lanes
            const float h = go * fast_tanh(c);
            if (k == 0) hdb[cur ^ 1][hoff(u)] = h;
        }
        if (wid == 0 && s >= 1) {                          // emission for time e = s-1
            const float ev = kreduce(dot16(wo, r));
            const int e = s - 1;
            if ((e & 7) == k) { if (e & 8) v1 = ev; else v0 = ev; }
            if ((s & (TILE - 1)) == 0 && m < NTAG) {       // flush e in [s-16, s-1]
                const int eA = s - TILE + k;
                eX[(t0 + ts * eA) * 8 + m] = v0;
                eX[(t0 + ts * (eA + 8)) * 8 + m] = v1;
            }
        }
        __syncthreads();
    }
}

// ======================= K3: Viterbi scan + backtrace =======================
// grid BSZ, block 64 (one wave): lane = next*8 + prev. ft = ef + eb (+b_out,
// folded into trv).
__global__ __launch_bounds__(64, 1)
void vit_kernel(const float* __restrict__ eft, const float* __restrict__ ebt,
                const float* __restrict__ b_out, const float* __restrict__ trans,
                float* __restrict__ out)
{
    const int b = blockIdx.x;
    const int lane = threadIdx.x;
    __shared__ __align__(16) float ftl[SEQ * 8];
    __shared__ int bptr_lds[SEQ * 8];

    {   // stage ef+eb: 2x16 KB coalesced
        const float4* sf = (const float4*)(eft + (size_t)b * (SEQ * 8));
        const float4* sb = (const float4*)(ebt + (size_t)b * (SEQ * 8));
        float4* dst = (float4*)ftl;
        #pragma unroll
        for (int i = 0; i < SEQ * 2 / 64; ++i) {
            float4 a = sf[lane + i * 64];
            const float4 c4 = sb[lane + i * 64];
            a.x += c4.x; a.y += c4.y; a.z += c4.z; a.w += c4.w;
            dst[lane + i * 64] = a;
        }
    }
    __syncthreads();

    const int next = lane >> 3;
    const int prev = lane & 7;
    const bool pv = (prev < NTAG);
    const bool nv = (next < NTAG);
    const float trv = (pv && nv) ? (trans[next * NTAG + prev] + b_out[next]) : -3.0e38f;
    float fvp = pv ? ((prev == BOSX) ? 0.0f : NEGC) : -3.0e38f;
    for (int t = 0; t < SEQ; ++t) {
        float m = fvp + trv;
        int am = prev;
        #pragma unroll
        for (int off = 1; off < 8; off <<= 1) {          // first-max-index semantics
            const float om = __shfl_xor(m, off);
            const int oa = __shfl_xor(am, off);
            if (om > m || (om == m && oa < am)) { m = om; am = oa; }
        }
        const float fvnew = m + ftl[t * 8 + next];
        if (prev == 0) bptr_lds[t * 8 + next] = am;
        fvp = __shfl(fvnew, prev << 3);
        if (!pv) fvp = -3.0e38f;
    }
    float term = pv ? (fvp + trans[EOSX * NTAG + prev]) : -3.0e38f;
    int am = prev;
    #pragma unroll
    for (int off = 1; off < 8; off <<= 1) {
        const float om = __shfl_xor(term, off);
        const int oa = __shfl_xor(am, off);
        if (om > term || (om == term && oa < am)) { term = om; am = oa; }
    }
    if (lane == 0) {
        out[b] = term;
        int cur = am;
        for (int t = SEQ - 1; t >= 0; --t) {
            out[BSZ + t * BSZ + b] = (float)cur;
            cur = bptr_lds[t * 8 + cur];
        }
    }
}

// ======================= launch =======================
template<typename XWT>
static void run_all(const int* sen, const float* emb,
                    const float* Wih_f, const float* Whh_f, const float* b_f,
                    const float* Wih_b, const float* Whh_b, const float* b_b,
                    const float* W_out, const float* b_out, const float* trans,
                    XWT* xw, float* eft, float* ebt, float* out, hipStream_t stream)
{
    proj_kernel<XWT><<<dim3(2 * BSZ, 2), dim3(1024), 0, stream>>>(
        sen, emb, Wih_f, b_f, Wih_b, b_b, xw);
    rec_kernel<XWT><<<dim3(2 * BSZ), dim3(1024), 0, stream>>>(
        Whh_f, Whh_b, W_out, xw, eft, ebt);
    vit_kernel<<<dim3(BSZ), dim3(64), 0, stream>>>(eft, ebt, b_out, trans, out);
}

extern "C" void kernel_launch(void* const* d_in, const int* in_sizes, int n_in,
                              void* d_out, int out_size, void* d_ws, size_t ws_size,
                              hipStream_t stream)
{
    const int*   sen   = (const int*)d_in[0];
    const float* emb   = (const float*)d_in[1];
    const float* Wih_f = (const float*)d_in[2];
    const float* Whh_f = (const float*)d_in[3];
    const float* b_f   = (const float*)d_in[4];
    const float* Wih_b = (const float*)d_in[5];
    const float* Whh_b = (const float*)d_in[6];
    const float* b_b   = (const float*)d_in[7];
    const float* W_out = (const float*)d_in[8];
    const float* b_out = (const float*)d_in[9];
    const float* trans = (const float*)d_in[10];
    float* out = (float*)d_out;

    char* ws = (char*)d_ws;
    const size_t xw_elems = (size_t)2 * BSZ * SEQ * H4;   // 67,108,864
    const size_t ft_bytes = (size_t)BSZ * SEQ * 8 * 4;    // 2 MB each

    if (ws_size >= xw_elems * 4 + 2 * ft_bytes) {
        float* xw = (float*)ws;
        float* eft = (float*)(ws + xw_elems * 4);
        float* ebt = (float*)(ws + xw_elems * 4 + ft_bytes);
        run_all<float>(sen, emb, Wih_f, Whh_f, b_f, Wih_b, Whh_b, b_b,
                       W_out, b_out, trans, xw, eft, ebt, out, stream);
    } else {
        __hip_bfloat16* xw = (__hip_bfloat16*)ws;
        float* eft = (float*)(ws + xw_elems * 2);
        float* ebt = (float*)(ws + xw_elems * 2 + ft_bytes);
        run_all<__hip_bfloat16>(sen, emb, Wih_f, Whh_f, b_f, Wih_b, Whh_b, b_b,
                                W_out, b_out, trans, xw, eft, ebt, out, stream);
    }
}

// Round 8
// 961.852 us; speedup vs baseline: 4.3254x; 1.2439x over previous
//
#include <hip/hip_runtime.h>
#include <hip/hip_bf16.h>
#include <math.h>
#include <type_traits>

#define SEQ  512
#define BSZ  128
#define EMBD 128
#define H4   512
#define HD   128
#define NTAG 7
#define BOSX 4
#define EOSX 5
#define NEGC (-10000.0f)
#define TILE 16

typedef float v2f __attribute__((ext_vector_type(2)));

template<typename T> __device__ __forceinline__ void st4(T* p, float4 v);
template<> __device__ __forceinline__ void st4<float>(float* p, float4 v) { *(float4*)p = v; }
template<> __device__ __forceinline__ void st4<__hip_bfloat16>(__hip_bfloat16* p, float4 v) {
    p[0] = __float2bfloat16(v.x); p[1] = __float2bfloat16(v.y);
    p[2] = __float2bfloat16(v.z); p[3] = __float2bfloat16(v.w);
}

// v_rcp_f32: 1 inst (~1e-6 rel err) — plain 1.0f/x compiles to the precise
// v_div_scale/fmas/fixup sequence (~10 insts), which R7 paid 5x/thread/step.
__device__ __forceinline__ float frcp(float x) { return __builtin_amdgcn_rcpf(x); }

template<int C> __device__ __forceinline__ float dppaddf(float x) {
    const int y = __builtin_amdgcn_update_dpp(0, __builtin_bit_cast(int, x), C, 0xF, 0xF, true);
    return x + __builtin_bit_cast(float, y);
}
template<int C> __device__ __forceinline__ float dppmovf(float x) {
    return __builtin_bit_cast(float,
        __builtin_amdgcn_update_dpp(0, __builtin_bit_cast(int, x), C, 0xF, 0xF, true));
}
// full k-reduce (broadcast result to all k-lanes); k = lane bits {0,1,3}
__device__ __forceinline__ float kreduce(float x) {
    x = dppaddf<0xB1>(x);   // quad_perm [1,0,3,2] : xor bit0
    x = dppaddf<0x4E>(x);   // quad_perm [2,3,0,1] : xor bit1
    x = dppaddf<0x128>(x);  // row_ror:8           : xor bit3
    return x;
}

// Chunked-skew LDS layout for h: chunk k (16 floats) at float offset 20*k ->
// the wave's 8 distinct chunk b128s cover all 32 banks exactly once.
#define CHUNK_STRIDE 20
#define ROW_STRIDE 160
__device__ __forceinline__ int hoff(int u) { return (u >> 4) * CHUNK_STRIDE + (u & 15); }

__device__ __forceinline__ float dot16(const v2f* __restrict__ w2, const float4* __restrict__ r) {
    v2f a = {0.f, 0.f};
    #pragma unroll
    for (int j = 0; j < 4; ++j) {
        v2f lo; lo.x = r[j].x; lo.y = r[j].y;
        v2f hi; hi.x = r[j].z; hi.y = r[j].w;
        a = __builtin_elementwise_fma(w2[2 * j], lo, a);
        a = __builtin_elementwise_fma(w2[2 * j + 1], hi, a);
    }
    return a.x + a.y;
}
__device__ __forceinline__ void ldw2(v2f* w2, const float4* wr) {
    #pragma unroll
    for (int j = 0; j < 4; ++j) {
        const float4 f4 = wr[j];
        w2[2 * j].x = f4.x;     w2[2 * j].y = f4.y;
        w2[2 * j + 1].x = f4.z; w2[2 * j + 1].y = f4.w;
    }
}

// =============== K1: fused projection + recurrence + emissions ===============
// grid 2*BSZ (1 block/CU), block 1024 = 128 u x 8 k (k = lane bits {0,1,3}).
// Phase A: this chain's xw[t][u][4] (512 t) -> global ws (L3-resident: R7 rec
// FETCH was 66 MB, L3 absorbs the 268 MB xw round-trip). No inter-kernel sync.
// Phase B: recurrence. Per step: 4 partial gate dots -> DPP REDUCE-SCATTER so
// each lane owns ONE gate -> ONE rcp+exp activation (R7: 4 redundant precise-
// div activations per lane = ~half the VALU issue) -> DPP all-gather -> c,h.
// Emissions for h_t computed by wave 0, flushed per 16 steps.
template<typename XWT>
__global__ __launch_bounds__(1024, 1)
void bilstm_kernel(const int* __restrict__ sen, const float* __restrict__ emb,
                   const float* __restrict__ Wih_f, const float* __restrict__ b_f,
                   const float* __restrict__ Wih_b, const float* __restrict__ b_b,
                   const float* __restrict__ Whh_f, const float* __restrict__ Whh_b,
                   const float* __restrict__ W_out,
                   XWT* __restrict__ xw, float* __restrict__ eft, float* __restrict__ ebt)
{
    const int tid = threadIdx.x;
    const int wid = tid >> 6;
    const int lane = tid & 63;
    const int k = (lane & 3) | ((lane >> 1) & 4);          // lane bits 0,1,3
    const int m = ((lane >> 2) & 1) | ((lane >> 3) & 6);   // lane bits 2,4,5
    const int u = wid * 8 + m;
    const bool bk0 = (lane & 1) != 0;                      // k bit0
    const bool bk1 = (lane & 2) != 0;                      // k bit1
    const int chain = blockIdx.x;
    const int dir = chain & 1;
    const int b = chain >> 1;

    __shared__ __align__(16) float smem[TILE * H4];        // 32 KB: xs (A) / xwt (B)
    __shared__ __align__(16) float hdb[2][ROW_STRIDE];

    XWT* __restrict__ xw_c = xw + (size_t)chain * (SEQ * H4);
    v2f w2[4][8];                                          // 64 VGPRs

    // ---------------- Phase A: input projection ----------------
    {
        const float* __restrict__ Wih  = dir ? Wih_b : Wih_f;
        const float* __restrict__ bias = dir ? b_b : b_f;
        #pragma unroll
        for (int g = 0; g < 4; ++g)
            ldw2(w2[g], (const float4*)(Wih + (g * HD + u) * EMBD + k * 16));
        float4 bj;
        bj.x = bias[u]; bj.y = bias[HD + u]; bj.z = bias[2 * HD + u]; bj.w = bias[3 * HD + u];

        for (int tt = 0; tt < SEQ; tt += 32) {
            {   // stage 32 embedding rows into chunk-skewed layout
                const int srow = tid >> 5;
                const int col = tid & 31;
                const int tok = sen[(tt + srow) * BSZ + b];
                const float4 v = ((const float4*)(emb + (size_t)tok * EMBD))[col];
                *(float4*)(&smem[srow * ROW_STRIDE + (col >> 2) * CHUNK_STRIDE + (col & 3) * 4]) = v;
            }
            __syncthreads();
            for (int i = 0; i < 32; ++i) {
                const float4* xr = (const float4*)(smem + i * ROW_STRIDE + k * CHUNK_STRIDE);
                float4 r[4];
                #pragma unroll
                for (int j = 0; j < 4; ++j) r[j] = xr[j];
                const float z0 = kreduce(dot16(w2[0], r));
                const float z1 = kreduce(dot16(w2[1], r));
                const float z2 = kreduce(dot16(w2[2], r));
                const float z3 = kreduce(dot16(w2[3], r));
                if (k == 0) {
                    float4 o; o.x = z0 + bj.x; o.y = z1 + bj.y; o.z = z2 + bj.z; o.w = z3 + bj.w;
                    st4(&xw_c[(tt + i) * H4 + u * 4], o);
                }
            }
            __syncthreads();
        }
    }

    // ---------------- Phase B: recurrence + emissions ----------------
    {
        const float* __restrict__ Whh = dir ? Whh_b : Whh_f;
        #pragma unroll
        for (int g = 0; g < 4; ++g)
            ldw2(w2[g], (const float4*)(Whh + (g * HD + u) * HD + k * 16));
        v2f wo[8];                                         // wave-0 emission weights
        {
            const int mm = (m < NTAG) ? m : 0;
            ldw2(wo, (const float4*)(W_out + mm * 256 + dir * HD + k * 16));
        }
        if (tid < 2 * ROW_STRIDE) ((float*)hdb)[tid] = 0.0f;
        float c = 0.0f, v0 = 0.0f, v1 = 0.0f;
        float* __restrict__ eX = (dir ? ebt : eft) + (size_t)b * (SEQ * 8);
        float (*xwt)[H4] = (float (*)[H4])smem;
        __syncthreads();

        const int t0 = dir ? (SEQ - 1) : 0;
        const int ts = dir ? -1 : 1;
        for (int s = 0; s <= SEQ; ++s) {
            if ((s & (TILE - 1)) == 0) {
                if (s < SEQ) {                             // stage xw for steps s..s+15
                    const int tg = t0 + ts * (s + wid);    // wave wid stages slot wid
                    float4* dst = (float4*)xwt[wid];
                    if constexpr (std::is_same_v<XWT, float>) {
                        const float4* src = (const float4*)(xw_c + tg * H4);
                        dst[lane] = src[lane];
                        dst[lane + 64] = src[lane + 64];
                    } else {
                        const uint4 raw = ((const uint4*)(xw_c + tg * H4))[lane];
                        const unsigned rr[4] = {raw.x, raw.y, raw.z, raw.w};
                        float4 lo4, hi4;
                        float* lp = (float*)&lo4; float* hp = (float*)&hi4;
                        #pragma unroll
                        for (int j = 0; j < 2; ++j) {
                            lp[2*j]   = __builtin_bit_cast(float, rr[j] << 16);
                            lp[2*j+1] = __builtin_bit_cast(float, rr[j] & 0xFFFF0000u);
                            hp[2*j]   = __builtin_bit_cast(float, rr[j+2] << 16);
                            hp[2*j+1] = __builtin_bit_cast(float, rr[j+2] & 0xFFFF0000u);
                        }
                        dst[2 * lane] = lo4;
                        dst[2 * lane + 1] = hi4;
                    }
                }
                __syncthreads();
            }
            const int cur = s & 1;
            float4 r[4];                                   // chunk k of h_{t-ts}
            {
                const float4* hr = (const float4*)(hdb[cur] + k * CHUNK_STRIDE);
                #pragma unroll
                for (int j = 0; j < 4; ++j) r[j] = hr[j];
            }
            if (s < SEQ) {
                const float4 xv = *(const float4*)(&xwt[s & (TILE - 1)][u * 4]);
                const float pi = dot16(w2[0], r);
                const float pf = dot16(w2[1], r);
                const float pg = dot16(w2[2], r);
                const float po = dot16(w2[3], r);
                // reduce-scatter: after 3 stages lane owns gate gid = (bk1,bk0)
                const float A = (bk0 ? pf : pi) + dppmovf<0xB1>(bk0 ? pi : pf);
                const float B = (bk0 ? po : pg) + dppmovf<0xB1>(bk0 ? pg : po);
                float z = (bk1 ? B : A) + dppmovf<0x4E>(bk1 ? A : B);
                z += dppmovf<0x128>(z);
                // add my gate's xw
                const float xlo = bk0 ? xv.y : xv.x;
                const float xhi = bk0 ? xv.w : xv.z;
                z += bk1 ? xhi : xlo;
                // one activation per lane (gate 2 = tanh via 2*sigma(2z)-1)
                const bool isg = bk1 && !bk0;
                const float x2 = isg ? (z + z) : z;
                float y = frcp(1.0f + __expf(-x2));
                y = isg ? (2.0f * y - 1.0f) : y;
                // all-gather the 4 activated gates
                const float r1 = dppmovf<0xB1>(y);
                const float r2 = dppmovf<0x4E>(y);
                const float r3 = dppmovf<0x4E>(r1);
                const float i0 = bk0 ? r1 : y,  i1 = bk0 ? y : r1;
                const float i2 = bk0 ? r3 : r2, i3 = bk0 ? r2 : r3;
                const float gi = bk1 ? i2 : i0;
                const float gf = bk1 ? i3 : i1;
                const float gg = bk1 ? i0 : i2;
                const float go = bk1 ? i1 : i3;
                c = gf * c + gi * gg;                      // redundant across k-lanes
                const float th = 2.0f * frcp(1.0f + __expf(-2.0f * c)) - 1.0f;
                const float h = go * th;
                if (k == 0) hdb[cur ^ 1][hoff(u)] = h;
            }
            if (wid == 0 && s >= 1) {                      // emission for time e = s-1
                const float ev = kreduce(dot16(wo, r));
                const int e = s - 1;
                if ((e & 7) == k) { if (e & 8) v1 = ev; else v0 = ev; }
                if ((s & (TILE - 1)) == 0 && m < NTAG) {   // flush e in [s-16, s-1]
                    const int eA = s - TILE + k;
                    eX[(t0 + ts * eA) * 8 + m] = v0;
                    eX[(t0 + ts * (eA + 8)) * 8 + m] = v1;
                }
            }
            __syncthreads();
        }
    }
}

// ======================= K2: Viterbi scan + backtrace =======================
// grid BSZ, block 64 (one wave): lane = next*8 + prev. ft = ef + eb (+b_out,
// folded into trv).
__global__ __launch_bounds__(64, 1)
void vit_kernel(const float* __restrict__ eft, const float* __restrict__ ebt,
                const float* __restrict__ b_out, const float* __restrict__ trans,
                float* __restrict__ out)
{
    const int b = blockIdx.x;
    const int lane = threadIdx.x;
    __shared__ __align__(16) float ftl[SEQ * 8];
    __shared__ int bptr_lds[SEQ * 8];

    {   // stage ef+eb: 2x16 KB coalesced
        const float4* sf = (const float4*)(eft + (size_t)b * (SEQ * 8));
        const float4* sb = (const float4*)(ebt + (size_t)b * (SEQ * 8));
        float4* dst = (float4*)ftl;
        #pragma unroll
        for (int i = 0; i < SEQ * 2 / 64; ++i) {
            float4 a = sf[lane + i * 64];
            const float4 c4 = sb[lane + i * 64];
            a.x += c4.x; a.y += c4.y; a.z += c4.z; a.w += c4.w;
            dst[lane + i * 64] = a;
        }
    }
    __syncthreads();

    const int next = lane >> 3;
    const int prev = lane & 7;
    const bool pv = (prev < NTAG);
    const bool nv = (next < NTAG);
    const float trv = (pv && nv) ? (trans[next * NTAG + prev] + b_out[next]) : -3.0e38f;
    float fvp = pv ? ((prev == BOSX) ? 0.0f : NEGC) : -3.0e38f;
    for (int t = 0; t < SEQ; ++t) {
        float m = fvp + trv;
        int am = prev;
        #pragma unroll
        for (int off = 1; off < 8; off <<= 1) {          // first-max-index semantics
            const float om = __shfl_xor(m, off);
            const int oa = __shfl_xor(am, off);
            if (om > m || (om == m && oa < am)) { m = om; am = oa; }
        }
        const float fvnew = m + ftl[t * 8 + next];
        if (prev == 0) bptr_lds[t * 8 + next] = am;
        fvp = __shfl(fvnew, prev << 3);
        if (!pv) fvp = -3.0e38f;
    }
    float term = pv ? (fvp + trans[EOSX * NTAG + prev]) : -3.0e38f;
    int am = prev;
    #pragma unroll
    for (int off = 1; off < 8; off <<= 1) {
        const float om = __shfl_xor(term, off);
        const int oa = __shfl_xor(am, off);
        if (om > term || (om == term && oa < am)) { term = om; am = oa; }
    }
    if (lane == 0) {
        out[b] = term;
        int cur = am;
        for (int t = SEQ - 1; t >= 0; --t) {
            out[BSZ + t * BSZ + b] = (float)cur;
            cur = bptr_lds[t * 8 + cur];
        }
    }
}

// ======================= launch =======================
extern "C" void kernel_launch(void* const* d_in, const int* in_sizes, int n_in,
                              void* d_out, int out_size, void* d_ws, size_t ws_size,
                              hipStream_t stream)
{
    const int*   sen   = (const int*)d_in[0];
    const float* emb   = (const float*)d_in[1];
    const float* Wih_f = (const float*)d_in[2];
    const float* Whh_f = (const float*)d_in[3];
    const float* b_f   = (const float*)d_in[4];
    const float* Wih_b = (const float*)d_in[5];
    const float* Whh_b = (const float*)d_in[6];
    const float* b_b   = (const float*)d_in[7];
    const float* W_out = (const float*)d_in[8];
    const float* b_out = (const float*)d_in[9];
    const float* trans = (const float*)d_in[10];
    float* out = (float*)d_out;

    char* ws = (char*)d_ws;
    const size_t xw_elems = (size_t)2 * BSZ * SEQ * H4;   // 67,108,864
    const size_t ft_bytes = (size_t)BSZ * SEQ * 8 * 4;    // 2 MB each

    if (ws_size >= xw_elems * 4 + 2 * ft_bytes) {
        float* xw = (float*)ws;
        float* eft = (float*)(ws + xw_elems * 4);
        float* ebt = (float*)(ws + xw_elems * 4 + ft_bytes);
        bilstm_kernel<float><<<dim3(2 * BSZ), dim3(1024), 0, stream>>>(
            sen, emb, Wih_f, b_f, Wih_b, b_b, Whh_f, Whh_b, W_out, xw, eft, ebt);
        vit_kernel<<<dim3(BSZ), dim3(64), 0, stream>>>(eft, ebt, b_out, trans, out);
    } else {
        __hip_bfloat16* xw = (__hip_bfloat16*)ws;
        float* eft = (float*)(ws + xw_elems * 2);
        float* ebt = (float*)(ws + xw_elems * 2 + ft_bytes);
        bilstm_kernel<__hip_bfloat16><<<dim3(2 * BSZ), dim3(1024), 0, stream>>>(
            sen, emb, Wih_f, b_f, Wih_b, b_b, Whh_f, Whh_b, W_out, xw, eft, ebt);
        vit_kernel<<<dim3(BSZ), dim3(64), 0, stream>>>(eft, ebt, b_out, trans, out);
    }
}